// Round 13
// baseline (489.542 us; speedup 1.0000x reference)
//
#include <hip/hip_runtime.h>
#include <cstdint>
#include <cstddef>

typedef __bf16 bf16_t;
typedef uint8_t u8;
typedef u8 u8x8 __attribute__((ext_vector_type(8)));
typedef u8 u8x4v __attribute__((ext_vector_type(4)));
typedef float f32x4 __attribute__((ext_vector_type(4)));

#define NEGV (-1e9f)

#define GLDS(gp, lp) __builtin_amdgcn_global_load_lds( \
    (const __attribute__((address_space(1))) void*)(gp), \
    (__attribute__((address_space(3))) void*)(lp), 16, 0, 0)

// ---------------- exact OCP e4m3fn encode/decode (hand-rolled, no header deps) ----------------
__device__ inline float fp8dec(u8 b) {
    int e = (b >> 3) & 15, m = b & 7;
    float v = e ? ldexpf((float)(8 + m), e - 10) : ldexpf((float)m, -9);
    return (b & 0x80) ? -v : v;
}
__device__ inline u8 f2fp8(float x) {
    uint32_t u = __float_as_uint(x);
    u8 s = (u >> 24) & 0x80;
    float a = fabsf(x);
    if (!(a >= 0.0009765625f)) return s;              // <2^-10 (or NaN) -> +-0
    if (a > 448.0f) return s | 0x7E;                  // clamp to 448
    int e = (int)(__float_as_uint(a) >> 23) - 127;
    if (e < -6) {                                     // denormal: m = rint(a*2^9)
        int m = (int)rintf(a * 512.0f);
        if (m >= 8) return s | 0x08;
        return s | (u8)m;
    }
    int m = (int)rintf(ldexpf(a, 3 - e));             // [8,16]
    if (m == 16) { m = 8; ++e; }
    return s | (u8)(((e + 7) << 3) | (m - 8));
}

// ============================================================ prep mega-kernel
struct PrepArgs {
    const float* w512src[8]; u8* w512dst[8];
    const float* w128src[2]; u8* w128dst[2];
    const float* logicF; const float* physF;
    u8* featsSb; u8* featsPb;
    const int* mask; uint32_t* bits;
    int* cntC; int* cntR; int* cntL; int* firstL; int* dist;
    float* pooled; float* hacc;
};

__global__ __launch_bounds__(256)
void k_prep(PrepArgs p) {
    __shared__ float tb[64][65];
    const int b = blockIdx.x, tid = threadIdx.x;
    if (b < 544) {
        // transpose-convert f32 [K][N] -> fp8 [N][K], 64x64 tiles
        const float* src; u8* dst; int K, tile;
        if (b < 512) { src = p.w512src[b >> 6]; dst = p.w512dst[b >> 6]; K = 512; tile = b & 63; }
        else { int bb = b - 512; src = p.w128src[bb >> 4]; dst = p.w128dst[bb >> 4]; K = 128; tile = bb & 15; }
        const int N = 512;
        int kt = tile >> 3, tc = tile & 7;
        int cx = tid & 63, ry = tid >> 6;
#pragma unroll
        for (int q = 0; q < 16; ++q) {
            int r = q * 4 + ry;
            tb[r][cx] = src[(size_t)(kt * 64 + r) * N + tc * 64 + cx];
        }
        __syncthreads();
#pragma unroll
        for (int q = 0; q < 16; ++q) {
            int r2 = q * 4 + ry;
            dst[(size_t)(tc * 64 + r2) * K + kt * 64 + cx] = f2fp8(tb[cx][r2]);
        }
    } else if (b < 672) {
        size_t e0 = (size_t)(b - 544) * 1024 + tid * 4;
        float4 v = *(const float4*)(p.logicF + e0);
        u8x4v o; o[0]=f2fp8(v.x); o[1]=f2fp8(v.y); o[2]=f2fp8(v.z); o[3]=f2fp8(v.w);
        *(u8x4v*)(p.featsSb + e0) = o;
    } else if (b < 2720) {
        size_t e0 = (size_t)(b - 672) * 1024 + tid * 4;
        float4 v = *(const float4*)(p.physF + e0);
        u8x4v o; o[0]=f2fp8(v.x); o[1]=f2fp8(v.y); o[2]=f2fp8(v.z); o[3]=f2fp8(v.w);
        *(u8x4v*)(p.featsPb + e0) = o;
    } else if (b < 2784) {
        int gid = (b - 2720) * 256 + tid;   // 0..16383
        p.cntC[gid] = 0; p.cntR[gid] = 0; p.firstL[gid] = 0x7fffffff;
        p.dist[gid] = (gid == 0) ? 0 : 16384;
        if (gid < 1024) { p.cntL[gid] = 0; p.pooled[gid] = 0.0f; }
        if (gid < 512) p.hacc[gid] = 0.0f;
    } else {
        // mask bit-pack: 2048 blocks x 256 threads, 32 elems/thread
        size_t w = (size_t)(b - 2784) * 256 + tid;   // word index, 524288 total
        const int4* q4 = (const int4*)(p.mask + w * 32);
        uint32_t bb = 0;
#pragma unroll
        for (int q = 0; q < 8; ++q) {
            int4 v = q4[q];
            bb |= (v.x != 0 ? 1u : 0u) << (q * 4);
            bb |= (v.y != 0 ? 1u : 0u) << (q * 4 + 1);
            bb |= (v.z != 0 ? 1u : 0u) << (q * 4 + 2);
            bb |= (v.w != 0 ? 1u : 0u) << (q * 4 + 3);
        }
        p.bits[w] = bb;
    }
}

// ============================================================ CSR histogram + trajectory (fused)
__global__ void k_hist3(const int* __restrict__ rowP, const int* __restrict__ colP,
                        const int* __restrict__ rowL, const int* __restrict__ colL,
                        int* cntC, int* cntR, int* cntL, int EP, int EL,
                        const int* __restrict__ topo, const int* __restrict__ acts,
                        int* __restrict__ lastArr, int* __restrict__ firstL) {
    int b = blockIdx.x;
    if (b < 1040) {
        int e = b * 256 + threadIdx.x;
        if (e < EP) atomicAdd(&cntC[colP[e]], 1);
        else if (e < 2 * EP) atomicAdd(&cntR[rowP[e - EP]], 1);
        else if (e < 2 * EP + EL) atomicAdd(&cntL[colL[e - 2 * EP]], 1);
    } else {
        int s = (b - 1040) * 256 + threadIdx.x;   // 0..1023
        int last = (s == 0) ? 0 : acts[topo[s - 1]];
        lastArr[s] = last;
        int a = acts[topo[s]];
        if (a != last) atomicMin(&firstL[last], s);
    }
}

__global__ __launch_bounds__(256)
void k_scan3(int* cntC, int* offC, int* curC,
             int* cntR, int* offR, int* curR,
             int* cntL, int* offL, int* curL) {
    __shared__ int ss[256];
    int tid = threadIdx.x;
    const int* cnt; int* off; int* cur; int n;
    if (blockIdx.x == 0)      { cnt = cntC; off = offC; cur = curC; n = 16384; }
    else if (blockIdx.x == 1) { cnt = cntR; off = offR; cur = curR; n = 16384; }
    else                      { cnt = cntL; off = offL; cur = curL; n = 1024; }
    int chunk = n / 256, base = tid * chunk, s = 0;
    for (int i = 0; i < chunk; ++i) s += cnt[base + i];
    ss[tid] = s; __syncthreads();
    for (int d = 1; d < 256; d <<= 1) {
        int v = (tid >= d) ? ss[tid - d] : 0;
        __syncthreads(); ss[tid] += v; __syncthreads();
    }
    int run = (tid == 0) ? 0 : ss[tid - 1];
    for (int i = 0; i < chunk; ++i) { off[base + i] = run; cur[base + i] = run; run += cnt[base + i]; }
    if (tid == 255) off[n] = run;
}

__global__ void k_scatter3(const int* __restrict__ rowP, const int* __restrict__ colP,
                           const int* __restrict__ rowL, const int* __restrict__ colL,
                           int* curC, int* curR, int* curL,
                           int* erowCP, int* ecolRP, int* erowL, int EP, int EL) {
    int e = blockIdx.x * 256 + threadIdx.x;
    if (e < EP) {
        int c = colP[e]; int q = atomicAdd(&curC[c], 1); erowCP[q] = rowP[e];
    } else if (e < 2 * EP) {
        int e2 = e - EP;
        int c = rowP[e2]; int q = atomicAdd(&curR[c], 1); ecolRP[q] = colP[e2];
    } else if (e < 2 * EP + EL) {
        int e3 = e - 2 * EP;
        int c = colL[e3]; int q = atomicAdd(&curL[c], 1); erowL[q] = rowL[e3];
    }
}

// ============================================================ BFS: one level per dispatch, full-GPU wide
__global__ __launch_bounds__(256)
void k_bfs_level(const int* __restrict__ offR, const int* __restrict__ ecol,
                 int* __restrict__ dist, int lev) {
    int j = blockIdx.x * 256 + threadIdx.x;
    if (dist[j] != lev) return;
    int e0 = offR[j], e1 = offR[j + 1];
    for (int e = e0; e < e1; ++e) {
        int v = ecol[e];
        if (dist[v] == 16384) dist[v] = lev + 1;
    }
}

__global__ __launch_bounds__(256)
void k_fmpack(const int* __restrict__ firstL, const int* __restrict__ dist, int* __restrict__ fm) {
    int j = blockIdx.x * 256 + threadIdx.x;
    int fl = firstL[j]; if (fl > 0xFFFF) fl = 0xFFFF;
    fm[j] = (fl << 16) | dist[j];
}

// ============================================================ GEMM fp8 (K_STEP=64, 2-buffer, swizzled, T1)
struct GemmDesc { const u8* A; const u8* B; const u8* Cin; void* O;
                  int N; int K; float scale; int relu; int obf; };
struct GemmPair { GemmDesc d0; GemmDesc d1; int split; };

__global__ __launch_bounds__(256)
void gemm_mfma(GemmPair args) {
    __shared__ u8 As[2][128 * 64];
    __shared__ u8 Bs[2][128 * 64];
    // T1: chunk-map flat block index so consecutive flat ids share an XCD L2 (nwg%8==0).
    const int nwg = gridDim.x * gridDim.y;
    const int cpx = nwg >> 3;
    const int pfl = blockIdx.y * gridDim.x + blockIdx.x;
    const int vfl = (pfl & 7) * cpx + (pfl >> 3);
    const int vbx = vfl % gridDim.x;
    const int vby = vfl / gridDim.x;
    const int inSet1 = (vby >= args.split);
    const GemmDesc g = inSet1 ? args.d1 : args.d0;
    const int my = vby - (inSet1 ? args.split : 0);
    const int m0 = my * 128, n0 = vbx * 128;
    const int tid = threadIdx.x, wave = tid >> 6, lane = tid & 63;
    const int wm = (wave >> 1) * 64, wn = (wave & 1) * 64;
    const int lr = lane & 15, lkq = lane >> 4;
    const int K = g.K;
    const int srr = wave * 16 + (lane >> 2);
    const int scb = (((lane & 3) ^ ((lane >> 2) & 3)) << 4);  // pre-swizzled global col byte
    const u8* Abase = g.A + (size_t)(m0 + srr) * K + scb;
    const u8* Bbase = g.B + (size_t)(n0 + srr) * K + scb;
    const size_t rstep = (size_t)64 * K;
    f32x4 acc[4][4] = {};

    auto stage = [&](int q, int k0) {
        GLDS(Abase + k0,         &As[q][(wave * 16) * 64]);
        GLDS(Abase + k0 + rstep, &As[q][(64 + wave * 16) * 64]);
        GLDS(Bbase + k0,         &Bs[q][(wave * 16) * 64]);
        GLDS(Bbase + k0 + rstep, &Bs[q][(64 + wave * 16) * 64]);
    };

    stage(0, 0);
    asm volatile("s_waitcnt vmcnt(0)" ::: "memory");
    __syncthreads();
    const int nt = K >> 6;
    for (int t = 0; t < nt; ++t) {
        int cur = t & 1;
        if (t + 1 < nt) stage(cur ^ 1, (t + 1) << 6);
#pragma unroll
        for (int kh = 0; kh < 2; ++kh) {
            long af[4], bf[4];
#pragma unroll
            for (int mi = 0; mi < 4; ++mi) {
                int r = wm + mi * 16 + lr;
                int pb = r * 64 + ((kh * 32 + lkq * 8) ^ ((r & 3) << 4));
                af[mi] = *(const long*)&As[cur][pb];
            }
#pragma unroll
            for (int ni = 0; ni < 4; ++ni) {
                int r = wn + ni * 16 + lr;
                int pb = r * 64 + ((kh * 32 + lkq * 8) ^ ((r & 3) << 4));
                bf[ni] = *(const long*)&Bs[cur][pb];
            }
#pragma unroll
            for (int mi = 0; mi < 4; ++mi)
#pragma unroll
                for (int ni = 0; ni < 4; ++ni)
                    acc[mi][ni] = __builtin_amdgcn_mfma_f32_16x16x32_fp8_fp8(af[mi], bf[ni], acc[mi][ni], 0, 0, 0);
        }
        asm volatile("s_waitcnt vmcnt(0)" ::: "memory");
        __syncthreads();
    }
    const int rb = m0 + wm + (lane >> 4) * 4;
    const int cb = n0 + wn + lr;
#pragma unroll
    for (int mi = 0; mi < 4; ++mi)
#pragma unroll
        for (int ni = 0; ni < 4; ++ni)
#pragma unroll
            for (int r = 0; r < 4; ++r) {
                int row = rb + mi * 16 + r;
                int col = cb + ni * 16;
                size_t idx = (size_t)row * g.N + col;
                float v = acc[mi][ni][r] * g.scale;
                if (g.Cin) v += fp8dec(g.Cin[idx]);
                if (g.relu) v = fmaxf(v, 0.0f);
                if (g.obf) ((bf16_t*)g.O)[idx] = (bf16_t)v;
                else       ((u8*)g.O)[idx] = f2fp8(v);
            }
}

// ============================================================ SpMM fp8 (fused logic+phys)
__global__ __launch_bounds__(256)
void k_spmm2(const u8* __restrict__ HL, const int* __restrict__ offL, const int* __restrict__ erowL, u8* __restrict__ XL,
             const u8* __restrict__ HP, const int* __restrict__ offP, const int* __restrict__ erowP, u8* __restrict__ XP) {
    int b = blockIdx.x;
    const u8* H; const int* off; const int* erow; u8* X; int c;
    int wib = threadIdx.x >> 6, lane = threadIdx.x & 63;
    if (b < 256) { H = HL; off = offL; erow = erowL; X = XL; c = b * 4 + wib; }
    else { b -= 256; H = HP; off = offP; erow = erowP; X = XP; c = b * 4 + wib; }
    int d0 = lane * 8;
    float acc[8] = {0,0,0,0,0,0,0,0};
    int e0 = off[c], e1 = off[c + 1];
    for (int e = e0; e < e1; ++e) {
        int r = erow[e];
        u8x8 h = *(const u8x8*)(H + (size_t)r * 512 + d0);
#pragma unroll
        for (int j = 0; j < 8; ++j) acc[j] += fp8dec(h[j]);
    }
    u8x8 own = *(const u8x8*)(H + (size_t)c * 512 + d0);
    u8x8 o;
#pragma unroll
    for (int j = 0; j < 8; ++j) o[j] = f2fp8(fp8dec(own[j]) + acc[j]);
    *(u8x8*)(X + (size_t)c * 512 + d0) = o;
}

// ============================================================ scan (one-pass online softmax, unchanged)
__global__ __launch_bounds__(256)
void k_scan2(const bf16_t* __restrict__ S, const uint32_t* __restrict__ bits,
             const int* __restrict__ fm, const int* __restrict__ topo,
             const int* __restrict__ acts, const int* __restrict__ lastA,
             float* __restrict__ slogp, float* __restrict__ sent) {
    typedef bf16_t bf16x8 __attribute__((ext_vector_type(8)));
    const int NPn = 16384, cloud = NPn - 1;
    __shared__ float msh[256], zsh[256], wsh[256];
    __shared__ int ash[256];
    const int s = blockIdx.x, tid = threadIdx.x;
    const int i = topo[s], a = acts[i], last = lastA[s];
    const bf16_t* Srow = S + (size_t)i * NPn;
    const uint32_t* brow = bits + (size_t)i * 512;
    const int ml = fm[last] & 0xFFFF;
    const int baseCloud = (brow[511] >> 31) & 1;
    const int lic = (last == cloud);
    if (lic && baseCloud) {
        if (tid == 0) {
            float M = (float)Srow[cloud];
            slogp[s] = (a == cloud) ? 0.0f : (NEGV - M);
            sent[s] = 0.0f;
        }
        return;
    }
    float m = -3.4e38f, Z = 0.0f, W = 0.0f;
    int any = 0;
    if (!lic) {
        for (int c = 0; c < 8; ++c) {
            int j0 = c * 2048 + tid * 8;
            bf16x8 sv = *(const bf16x8*)(Srow + j0);
            uint32_t b8 = (brow[j0 >> 5] >> (j0 & 24)) & 0xFFu;
            int4 f0 = *(const int4*)(fm + j0);
            int4 f1 = *(const int4*)(fm + j0 + 4);
            int fj[8] = {f0.x, f0.y, f0.z, f0.w, f1.x, f1.y, f1.z, f1.w};
#pragma unroll
            for (int q = 0; q < 8; ++q) {
                int j = j0 + q;
                bool alw = ((b8 >> q) & 1) && ((fj[q] & 0xFFFF) >= ml)
                           && (j == last || (((unsigned)fj[q]) >> 16) >= (unsigned)s);
                if (alw) {
                    any = 1;
                    float l = (float)sv[q];
                    if (l > m) {
                        float d = m - l, ce = expf(d);
                        W = ce * (W + d * Z);
                        Z = ce * Z + 1.0f;
                        m = l;
                    } else {
                        float t = l - m, e = expf(t);
                        Z += e; W += t * e;
                    }
                }
            }
        }
    }
    msh[tid] = m; zsh[tid] = Z; wsh[tid] = W; ash[tid] = any;
    __syncthreads();
    for (int st = 128; st > 0; st >>= 1) {
        if (tid < st) {
            float m1 = msh[tid], Z1 = zsh[tid], W1 = wsh[tid];
            float m2 = msh[tid + st], Z2 = zsh[tid + st], W2 = wsh[tid + st];
            float M2 = fmaxf(m1, m2);
            float e1 = expf(m1 - M2), e2 = expf(m2 - M2);
            zsh[tid] = e1 * Z1 + e2 * Z2;
            wsh[tid] = e1 * (W1 + (m1 - M2) * Z1) + e2 * (W2 + (m2 - M2) * Z2);
            msh[tid] = M2;
            ash[tid] |= ash[tid + st];
        }
        __syncthreads();
    }
    if (tid != 0) return;
    if (ash[0]) {
        float M = msh[0], Zt = zsh[0], Wt = wsh[0];
        float logZ = logf(Zt);
        int fa = fm[a];
        bool alwa = ((brow[a >> 5] >> (a & 31)) & 1) && ((fa & 0xFFFF) >= ml)
                    && (a == last || (((unsigned)fa) >> 16) >= (unsigned)s);
        float la = alwa ? (float)Srow[a] : NEGV;
        slogp[s] = la - M - logZ;
        sent[s] = logZ - Wt / Zt;
        return;
    }
    int baseLast = (brow[last >> 5] >> (last & 31)) & 1;
    if (baseLast) { float M = (float)Srow[last]; slogp[s] = (a == last) ? 0.0f : (NEGV - M); sent[s] = 0.0f; return; }
    if (baseCloud) { float M = (float)Srow[cloud]; slogp[s] = (a == cloud) ? 0.0f : (NEGV - M); sent[s] = 0.0f; return; }
    float mm = -3.4e38f, ZZ = 0.0f, WW = 0.0f;
    for (int j = 0; j < NPn; ++j) {
        if ((brow[j >> 5] >> (j & 31)) & 1) {
            float l = (float)Srow[j];
            if (l > mm) { float d = mm - l, ce = expf(d); WW = ce * (WW + d * ZZ); ZZ = ce * ZZ + 1.0f; mm = l; }
            else { float t = l - mm, e = expf(t); ZZ += e; WW += t * e; }
        }
    }
    if (ZZ == 0.0f) { slogp[s] = -logf((float)NPn); sent[s] = logf((float)NPn); return; }
    float logZ = logf(ZZ);
    int ba = (brow[a >> 5] >> (a & 31)) & 1;
    float la = ba ? (float)Srow[a] : NEGV;
    slogp[s] = la - mm - logZ;
    sent[s] = logZ - WW / ZZ;
}

// ============================================================ value head + final
__global__ __launch_bounds__(256)
void k_pool2(const u8* __restrict__ HL, const u8* __restrict__ HP, float* __restrict__ pooled) {
    int b = blockIdx.x, tid = threadIdx.x;
    const u8* H; float* dst; int R, bb, ng; float inv;
    if (b < 16) { H = HL; dst = pooled; R = 1024; inv = 1.0f / 1024.0f; bb = b; ng = 16; }
    else { H = HP; dst = pooled + 512; R = 16384; inv = 1.0f / 16384.0f; bb = b - 16; ng = 128; }
    float a0 = 0, a1 = 0;
    for (int r = bb; r < R; r += ng) {
        a0 += fp8dec(H[(size_t)r * 512 + tid]);
        a1 += fp8dec(H[(size_t)r * 512 + tid + 256]);
    }
    atomicAdd(&dst[tid], a0 * inv);
    atomicAdd(&dst[tid + 256], a1 * inv);
}

__global__ __launch_bounds__(256)
void k_vpart(const float* __restrict__ pooled, const float* __restrict__ Wc1, float* __restrict__ hacc) {
    __shared__ float pk[128];
    int b = blockIdx.x, tid = threadIdx.x;
    int k0 = b * 128;
    if (tid < 128) pk[tid] = pooled[k0 + tid];
    __syncthreads();
    float a0 = 0, a1 = 0;
    for (int kk = 0; kk < 128; ++kk) {
        float pv = pk[kk];
        const float* wr = Wc1 + (size_t)(k0 + kk) * 512;
        a0 += pv * wr[tid];
        a1 += pv * wr[tid + 256];
    }
    atomicAdd(&hacc[tid], a0);
    atomicAdd(&hacc[tid + 256], a1);
}

__global__ __launch_bounds__(256)
void k_epilogue(const float* __restrict__ slogp, const float* __restrict__ sent,
                const float* __restrict__ hacc, const float* __restrict__ bc1,
                const float* __restrict__ wc2, float* __restrict__ out) {
    __shared__ float s1[256], s2[256], s3[256];
    int tid = threadIdx.x;
    float a = 0, b = 0;
    for (int k = tid; k < 1024; k += 256) { a += slogp[k]; b += sent[k]; }
    float v = fmaxf(hacc[tid] + bc1[tid], 0.0f) * wc2[tid]
            + fmaxf(hacc[tid + 256] + bc1[tid + 256], 0.0f) * wc2[tid + 256];
    s1[tid] = a; s2[tid] = b; s3[tid] = v;
    __syncthreads();
    for (int st = 128; st > 0; st >>= 1) {
        if (tid < st) { s1[tid] += s1[tid + st]; s2[tid] += s2[tid + st]; s3[tid] += s3[tid + st]; }
        __syncthreads();
    }
    if (tid == 0) { out[0] = s1[0]; out[1] = s2[0]; out[2] = s3[0]; }
}

// =======================================================================
extern "C" void kernel_launch(void* const* d_in, const int* in_sizes, int n_in,
                              void* d_out, int out_size, void* d_ws, size_t ws_size,
                              hipStream_t stream) {
    (void)n_in; (void)out_size; (void)ws_size; (void)in_sizes;
    const int MS = 1024, NP = 16384, EL = 4096, EP = 131072, D = 512;

    const int* logicE = (const int*)d_in[0];
    const float* logicF = (const float*)d_in[1];
    const int* physE = (const int*)d_in[2];
    const float* physF = (const float*)d_in[3];
    const int* acts = (const int*)d_in[4];
    const int* mask = (const int*)d_in[5];       // bool -> int32 on device
    const int* topo = (const int*)d_in[6];
    const float* Ws_in = (const float*)d_in[7];
    const float* Ws_out = (const float*)d_in[8];
    const float* Wp_in = (const float*)d_in[9];
    const float* Wp_out = (const float*)d_in[10];
    const float* sA1 = (const float*)d_in[11];
    const float* sA2 = (const float*)d_in[12];
    const float* pA1 = (const float*)d_in[13];
    const float* pA2 = (const float*)d_in[14];
    const float* Wq = (const float*)d_in[15];
    const float* Wk = (const float*)d_in[16];
    const float* Wc1 = (const float*)d_in[17];
    const float* bc1 = (const float*)d_in[18];
    const float* wc2 = (const float*)d_in[19];
    float* out = (float*)d_out;

    char* wsb = (char*)d_ws;
    size_t off = 0;
    auto alloc = [&](size_t bytes) -> void* {
        off = (off + 255) & ~(size_t)255;
        void* p = wsb + off; off += bytes; return p;
    };

    bf16_t* S_bf  = (bf16_t*)alloc((size_t)MS * NP * 2);
    u8* PB0     = (u8*)alloc((size_t)NP * D);
    u8* PB1     = (u8*)alloc((size_t)NP * D);
    u8* PB2     = (u8*)alloc((size_t)NP * D);
    u8* LB0     = (u8*)alloc((size_t)MS * D);
    u8* LB1     = (u8*)alloc((size_t)MS * D);
    u8* LB2     = (u8*)alloc((size_t)MS * D);
    u8* featsSb = (u8*)alloc((size_t)MS * 128);
    u8* featsPb = (u8*)alloc((size_t)NP * 128);
    u8* WsinT   = (u8*)alloc(512 * 128);
    u8* WpinT   = (u8*)alloc(512 * 128);
    u8* WsoutT  = (u8*)alloc(512 * 512);
    u8* sA1T    = (u8*)alloc(512 * 512);
    u8* sA2T    = (u8*)alloc(512 * 512);
    u8* WqT     = (u8*)alloc(512 * 512);
    u8* WpoutT  = (u8*)alloc(512 * 512);
    u8* pA1T    = (u8*)alloc(512 * 512);
    u8* pA2T    = (u8*)alloc(512 * 512);
    u8* WkT     = (u8*)alloc(512 * 512);
    uint32_t* bits = (uint32_t*)alloc((size_t)MS * NP / 8);   // 2 MB
    int* cntC  = (int*)alloc(NP * 4);
    int* offC  = (int*)alloc((NP + 1) * 4);
    int* curC  = (int*)alloc(NP * 4);
    int* cntR  = (int*)alloc(NP * 4);
    int* offR  = (int*)alloc((NP + 1) * 4);
    int* curR  = (int*)alloc(NP * 4);
    int* cntL  = (int*)alloc(MS * 4);
    int* offL  = (int*)alloc((MS + 1) * 4);
    int* curL  = (int*)alloc(MS * 4);
    int* erowCP = (int*)alloc(EP * 4);
    int* ecolRP = (int*)alloc(EP * 4);
    int* erowL  = (int*)alloc(EL * 4);
    int* firstL = (int*)alloc(NP * 4);
    int* lastA  = (int*)alloc(MS * 4);
    int* dist   = (int*)alloc(NP * 4);
    int* fm     = (int*)alloc(NP * 4);
    float* slogp = (float*)alloc(MS * 4);
    float* sentb = (float*)alloc(MS * 4);
    float* pooled = (float*)alloc(1024 * 4);
    float* hacc   = (float*)alloc(512 * 4);

    const int* rowP = physE;  const int* colP = physE + EP;
    const int* rowL = logicE; const int* colL = logicE + EL;

    // 1. prep (transposes + feat converts + mask bit-pack + zero-init)
    {
        PrepArgs p;
        const float* s512[8] = {Ws_out, sA1, sA2, Wq, Wp_out, pA1, pA2, Wk};
        u8* d512[8] = {WsoutT, sA1T, sA2T, WqT, WpoutT, pA1T, pA2T, WkT};
        for (int q = 0; q < 8; ++q) { p.w512src[q] = s512[q]; p.w512dst[q] = d512[q]; }
        p.w128src[0] = Ws_in; p.w128dst[0] = WsinT;
        p.w128src[1] = Wp_in; p.w128dst[1] = WpinT;
        p.logicF = logicF; p.physF = physF; p.featsSb = featsSb; p.featsPb = featsPb;
        p.mask = mask; p.bits = bits;
        p.cntC = cntC; p.cntR = cntR; p.cntL = cntL; p.firstL = firstL; p.dist = dist;
        p.pooled = pooled; p.hacc = hacc;
        hipLaunchKernelGGL(k_prep, dim3(4832), dim3(256), 0, stream, p);
    }
    // 2. CSR histogram + trajectory (fused)
    hipLaunchKernelGGL(k_hist3, dim3(1044), dim3(256), 0, stream,
                       rowP, colP, rowL, colL, cntC, cntR, cntL, EP, EL,
                       topo, acts, lastA, firstL);
    // 3-4. offsets + scatter
    hipLaunchKernelGGL(k_scan3, dim3(3), dim3(256), 0, stream,
                       cntC, offC, curC, cntR, offR, curR, cntL, offL, curL);
    hipLaunchKernelGGL(k_scatter3, dim3((2 * EP + EL) / 256), dim3(256), 0, stream,
                       rowP, colP, rowL, colL, curC, curR, curL, erowCP, ecolRP, erowL, EP, EL);
    // 5. BFS: 16 wide level dispatches (== 16 bounded Bellman-Ford iterations), then fm pack
    for (int lev = 0; lev < 16; ++lev)
        hipLaunchKernelGGL(k_bfs_level, dim3(64), dim3(256), 0, stream, offR, ecolRP, dist, lev);
    hipLaunchKernelGGL(k_fmpack, dim3(64), dim3(256), 0, stream, firstL, dist, fm);

    auto gemm2 = [&](const u8* A0, const u8* B0, const u8* C0, void* O0, float sc0,
                     const u8* A1, const u8* B1, const u8* C1, void* O1, float sc1,
                     int K, int relu) {
        GemmPair gp;
        gp.d0 = {A0, B0, C0, O0, 512, K, sc0, relu, 0};
        gp.d1 = {A1, B1, C1, O1, 512, K, sc1, relu, 0};
        gp.split = 8;
        hipLaunchKernelGGL(gemm_mfma, dim3(4, 136), dim3(256), 0, stream, gp);
    };

    // 6. h1 = relu(feats @ Win)
    gemm2(featsSb, WsinT, nullptr, LB0, 1.0f, featsPb, WpinT, nullptr, PB0, 1.0f, 128, 1);
    // 7. x = h1 + agg
    hipLaunchKernelGGL(k_spmm2, dim3(256 + 4096), dim3(256), 0, stream,
                       LB0, offL, erowL, LB1, PB0, offC, erowCP, PB1);
    // 8. h2 = relu(x @ Wout)
    gemm2(LB1, WsoutT, nullptr, LB0, 1.0f, PB1, WpoutT, nullptr, PB0, 1.0f, 512, 1);
    // 9. t = relu(h2 @ A1)
    gemm2(LB0, sA1T, nullptr, LB1, 1.0f, PB0, pA1T, nullptr, PB1, 1.0f, 512, 1);
    // 10. h = h2 + t @ A2
    gemm2(LB1, sA2T, LB0, LB2, 1.0f, PB1, pA2T, PB0, PB2, 1.0f, 512, 0);
    // 11. pooling
    hipLaunchKernelGGL(k_pool2, dim3(144), dim3(256), 0, stream, LB2, PB2, pooled);
    // 12. q = (h_s @ Wq)/sqrt(D);  Kp = h_p @ Wk
    gemm2(LB2, WqT, nullptr, LB1, 0.044194173824159216f, PB2, WkT, nullptr, PB1, 1.0f, 512, 0);
    // 13. S = q @ Kp^T   (bf16 output)
    {
        GemmPair gp;
        gp.d0 = {LB1, PB1, nullptr, S_bf, NP, 512, 1.0f, 0, 1};
        gp.d1 = gp.d0;
        gp.split = 1000;
        hipLaunchKernelGGL(gemm_mfma, dim3(128, 8), dim3(256), 0, stream, gp);
    }
    // 14. scan
    hipLaunchKernelGGL(k_scan2, dim3(MS), dim3(256), 0, stream,
                       S_bf, bits, fm, topo, acts, lastA, slogp, sentb);
    // 15-16. value head + final
    hipLaunchKernelGGL(k_vpart, dim3(8), dim3(256), 0, stream, pooled, Wc1, hacc);
    hipLaunchKernelGGL(k_epilogue, dim3(1), dim3(256), 0, stream, slogp, sentb, hacc, bc1, wc2, out);
}

// Round 15
// 378.064 us; speedup vs baseline: 1.2949x; 1.2949x over previous
//
#include <hip/hip_runtime.h>
#include <cstdint>
#include <cstddef>

typedef __bf16 bf16_t;
typedef uint8_t u8;
typedef u8 u8x4v __attribute__((ext_vector_type(4)));
typedef float f32x4 __attribute__((ext_vector_type(4)));

#define NEGV (-1e9f)

#define GLDS(gp, lp) __builtin_amdgcn_global_load_lds( \
    (const __attribute__((address_space(1))) void*)(gp), \
    (__attribute__((address_space(3))) void*)(lp), 16, 0, 0)

// ---------------- hardware OCP e4m3fn converts (gfx950 v_cvt, 1 VALU op each) ----------------
// byte_sel must be an instruction immediate -> template parameter.
template<int SEL>
__device__ inline float fp8decw(uint32_t w) { return __builtin_amdgcn_cvt_f32_fp8((int)w, SEL); }
__device__ inline float fp8dec(u8 b) { return __builtin_amdgcn_cvt_f32_fp8((int)b, 0); }
__device__ inline u8 f2fp8(float x) {
    return (u8)(__builtin_amdgcn_cvt_pk_fp8_f32(x, x, 0, false) & 0xFF);
}

// ============================================================ prep mega-kernel
struct PrepArgs {
    const float* w512src[8]; u8* w512dst[8];
    const float* w128src[2]; u8* w128dst[2];
    const float* logicF; const float* physF;
    u8* featsSb; u8* featsPb;
    const int* mask; uint32_t* bits;
    int* cntC; int* cntR; int* cntL; int* firstL; int* dist;
    float* pooled; float* hacc;
};

__global__ __launch_bounds__(256)
void k_prep(PrepArgs p) {
    __shared__ float tb[64][65];
    const int b = blockIdx.x, tid = threadIdx.x;
    if (b < 544) {
        // transpose-convert f32 [K][N] -> fp8 [N][K], 64x64 tiles
        const float* src; u8* dst; int K, tile;
        if (b < 512) { src = p.w512src[b >> 6]; dst = p.w512dst[b >> 6]; K = 512; tile = b & 63; }
        else { int bb = b - 512; src = p.w128src[bb >> 4]; dst = p.w128dst[bb >> 4]; K = 128; tile = bb & 15; }
        const int N = 512;
        int kt = tile >> 3, tc = tile & 7;
        int cx = tid & 63, ry = tid >> 6;
#pragma unroll
        for (int q = 0; q < 16; ++q) {
            int r = q * 4 + ry;
            tb[r][cx] = src[(size_t)(kt * 64 + r) * N + tc * 64 + cx];
        }
        __syncthreads();
#pragma unroll
        for (int q = 0; q < 16; ++q) {
            int r2 = q * 4 + ry;
            dst[(size_t)(tc * 64 + r2) * K + kt * 64 + cx] = f2fp8(tb[cx][r2]);
        }
    } else if (b < 672) {
        size_t e0 = (size_t)(b - 544) * 1024 + tid * 4;
        float4 v = *(const float4*)(p.logicF + e0);
        int pk = __builtin_amdgcn_cvt_pk_fp8_f32(v.x, v.y, 0, false);
        pk = __builtin_amdgcn_cvt_pk_fp8_f32(v.z, v.w, pk, true);
        *(uint32_t*)(p.featsSb + e0) = (uint32_t)pk;
    } else if (b < 2720) {
        size_t e0 = (size_t)(b - 672) * 1024 + tid * 4;
        float4 v = *(const float4*)(p.physF + e0);
        int pk = __builtin_amdgcn_cvt_pk_fp8_f32(v.x, v.y, 0, false);
        pk = __builtin_amdgcn_cvt_pk_fp8_f32(v.z, v.w, pk, true);
        *(uint32_t*)(p.featsPb + e0) = (uint32_t)pk;
    } else if (b < 2784) {
        int gid = (b - 2720) * 256 + tid;   // 0..16383
        p.cntC[gid] = 0; p.cntR[gid] = 0; p.firstL[gid] = 0x7fffffff;
        p.dist[gid] = (gid == 0) ? 0 : 16384;
        if (gid < 1024) { p.cntL[gid] = 0; p.pooled[gid] = 0.0f; }
        if (gid < 512) p.hacc[gid] = 0.0f;
    } else {
        // mask bit-pack: 2048 blocks x 256 threads, 32 elems/thread
        size_t w = (size_t)(b - 2784) * 256 + tid;   // word index, 524288 total
        const int4* q4 = (const int4*)(p.mask + w * 32);
        uint32_t bb = 0;
#pragma unroll
        for (int q = 0; q < 8; ++q) {
            int4 v = q4[q];
            bb |= (v.x != 0 ? 1u : 0u) << (q * 4);
            bb |= (v.y != 0 ? 1u : 0u) << (q * 4 + 1);
            bb |= (v.z != 0 ? 1u : 0u) << (q * 4 + 2);
            bb |= (v.w != 0 ? 1u : 0u) << (q * 4 + 3);
        }
        p.bits[w] = bb;
    }
}

// ============================================================ CSR histogram + trajectory (fused)
__global__ void k_hist3(const int* __restrict__ rowP, const int* __restrict__ colP,
                        const int* __restrict__ rowL, const int* __restrict__ colL,
                        int* cntC, int* cntR, int* cntL, int EP, int EL,
                        const int* __restrict__ topo, const int* __restrict__ acts,
                        int* __restrict__ lastArr, int* __restrict__ firstL) {
    int b = blockIdx.x;
    if (b < 1040) {
        int e = b * 256 + threadIdx.x;
        if (e < EP) atomicAdd(&cntC[colP[e]], 1);
        else if (e < 2 * EP) atomicAdd(&cntR[rowP[e - EP]], 1);
        else if (e < 2 * EP + EL) atomicAdd(&cntL[colL[e - 2 * EP]], 1);
    } else {
        int s = (b - 1040) * 256 + threadIdx.x;   // 0..1023
        int last = (s == 0) ? 0 : acts[topo[s - 1]];
        lastArr[s] = last;
        int a = acts[topo[s]];
        if (a != last) atomicMin(&firstL[last], s);
    }
}

__global__ __launch_bounds__(256)
void k_scan3(int* cntC, int* offC, int* curC,
             int* cntR, int* offR, int* curR,
             int* cntL, int* offL, int* curL) {
    __shared__ int ss[256];
    int tid = threadIdx.x;
    const int* cnt; int* off; int* cur; int n;
    if (blockIdx.x == 0)      { cnt = cntC; off = offC; cur = curC; n = 16384; }
    else if (blockIdx.x == 1) { cnt = cntR; off = offR; cur = curR; n = 16384; }
    else                      { cnt = cntL; off = offL; cur = curL; n = 1024; }
    int chunk = n / 256, base = tid * chunk, s = 0;
    for (int i = 0; i < chunk; ++i) s += cnt[base + i];
    ss[tid] = s; __syncthreads();
    for (int d = 1; d < 256; d <<= 1) {
        int v = (tid >= d) ? ss[tid - d] : 0;
        __syncthreads(); ss[tid] += v; __syncthreads();
    }
    int run = (tid == 0) ? 0 : ss[tid - 1];
    for (int i = 0; i < chunk; ++i) { off[base + i] = run; cur[base + i] = run; run += cnt[base + i]; }
    if (tid == 255) off[n] = run;
}

__global__ void k_scatter3(const int* __restrict__ rowP, const int* __restrict__ colP,
                           const int* __restrict__ rowL, const int* __restrict__ colL,
                           int* curC, int* curR, int* curL,
                           int* erowCP, int* ecolRP, int* erowL, int EP, int EL) {
    int e = blockIdx.x * 256 + threadIdx.x;
    if (e < EP) {
        int c = colP[e]; int q = atomicAdd(&curC[c], 1); erowCP[q] = rowP[e];
    } else if (e < 2 * EP) {
        int e2 = e - EP;
        int c = rowP[e2]; int q = atomicAdd(&curR[c], 1); ecolRP[q] = colP[e2];
    } else if (e < 2 * EP + EL) {
        int e3 = e - 2 * EP;
        int c = colL[e3]; int q = atomicAdd(&curL[c], 1); erowL[q] = rowL[e3];
    }
}

// ============================================================ BFS: one level per dispatch, full-GPU wide
__global__ __launch_bounds__(256)
void k_bfs_level(const int* __restrict__ offR, const int* __restrict__ ecol,
                 int* __restrict__ dist, int lev) {
    int j = blockIdx.x * 256 + threadIdx.x;
    if (dist[j] != lev) return;
    int e0 = offR[j], e1 = offR[j + 1];
    for (int e = e0; e < e1; ++e) {
        int v = ecol[e];
        if (dist[v] == 16384) dist[v] = lev + 1;
    }
}

__global__ __launch_bounds__(256)
void k_fmpack(const int* __restrict__ firstL, const int* __restrict__ dist, int* __restrict__ fm) {
    int j = blockIdx.x * 256 + threadIdx.x;
    int fl = firstL[j]; if (fl > 0xFFFF) fl = 0xFFFF;
    fm[j] = (fl << 16) | dist[j];
}

// ============================================================ GEMM fp8 (K_STEP=64, 2-buffer, swizzled, T1)
struct GemmDesc { const u8* A; const u8* B; const u8* Cin; void* O;
                  int N; int K; float scale; int relu; int obf; };
struct GemmPair { GemmDesc d0; GemmDesc d1; int split; };

__global__ __launch_bounds__(256)
void gemm_mfma(GemmPair args) {
    __shared__ u8 As[2][128 * 64];
    __shared__ u8 Bs[2][128 * 64];
    // T1: chunk-map flat block index so consecutive flat ids share an XCD L2 (nwg%8==0).
    const int nwg = gridDim.x * gridDim.y;
    const int cpx = nwg >> 3;
    const int pfl = blockIdx.y * gridDim.x + blockIdx.x;
    const int vfl = (pfl & 7) * cpx + (pfl >> 3);
    const int vbx = vfl % gridDim.x;
    const int vby = vfl / gridDim.x;
    const int inSet1 = (vby >= args.split);
    const GemmDesc g = inSet1 ? args.d1 : args.d0;
    const int my = vby - (inSet1 ? args.split : 0);
    const int m0 = my * 128, n0 = vbx * 128;
    const int tid = threadIdx.x, wave = tid >> 6, lane = tid & 63;
    const int wm = (wave >> 1) * 64, wn = (wave & 1) * 64;
    const int lr = lane & 15, lkq = lane >> 4;
    const int K = g.K;
    const int srr = wave * 16 + (lane >> 2);
    const int scb = (((lane & 3) ^ ((lane >> 2) & 3)) << 4);  // pre-swizzled global col byte
    const u8* Abase = g.A + (size_t)(m0 + srr) * K + scb;
    const u8* Bbase = g.B + (size_t)(n0 + srr) * K + scb;
    const size_t rstep = (size_t)64 * K;
    f32x4 acc[4][4] = {};

    auto stage = [&](int q, int k0) {
        GLDS(Abase + k0,         &As[q][(wave * 16) * 64]);
        GLDS(Abase + k0 + rstep, &As[q][(64 + wave * 16) * 64]);
        GLDS(Bbase + k0,         &Bs[q][(wave * 16) * 64]);
        GLDS(Bbase + k0 + rstep, &Bs[q][(64 + wave * 16) * 64]);
    };

    stage(0, 0);
    asm volatile("s_waitcnt vmcnt(0)" ::: "memory");
    __syncthreads();
    const int nt = K >> 6;
    for (int t = 0; t < nt; ++t) {
        int cur = t & 1;
        if (t + 1 < nt) stage(cur ^ 1, (t + 1) << 6);
#pragma unroll
        for (int kh = 0; kh < 2; ++kh) {
            long af[4], bf[4];
#pragma unroll
            for (int mi = 0; mi < 4; ++mi) {
                int r = wm + mi * 16 + lr;
                int pb = r * 64 + ((kh * 32 + lkq * 8) ^ ((r & 3) << 4));
                af[mi] = *(const long*)&As[cur][pb];
            }
#pragma unroll
            for (int ni = 0; ni < 4; ++ni) {
                int r = wn + ni * 16 + lr;
                int pb = r * 64 + ((kh * 32 + lkq * 8) ^ ((r & 3) << 4));
                bf[ni] = *(const long*)&Bs[cur][pb];
            }
#pragma unroll
            for (int mi = 0; mi < 4; ++mi)
#pragma unroll
                for (int ni = 0; ni < 4; ++ni)
                    acc[mi][ni] = __builtin_amdgcn_mfma_f32_16x16x32_fp8_fp8(af[mi], bf[ni], acc[mi][ni], 0, 0, 0);
        }
        asm volatile("s_waitcnt vmcnt(0)" ::: "memory");
        __syncthreads();
    }
    const int rb = m0 + wm + (lane >> 4) * 4;
    const int cb = n0 + wn + lr;
#pragma unroll
    for (int mi = 0; mi < 4; ++mi)
#pragma unroll
        for (int ni = 0; ni < 4; ++ni)
#pragma unroll
            for (int r = 0; r < 4; ++r) {
                int row = rb + mi * 16 + r;
                int col = cb + ni * 16;
                size_t idx = (size_t)row * g.N + col;
                float v = acc[mi][ni][r] * g.scale;
                if (g.Cin) v += fp8dec(g.Cin[idx]);
                if (g.relu) v = fmaxf(v, 0.0f);
                if (g.obf) ((bf16_t*)g.O)[idx] = (bf16_t)v;
                else       ((u8*)g.O)[idx] = f2fp8(v);
            }
}

// ============================================================ SpMM fp8 (fused logic+phys, hw cvt)
__global__ __launch_bounds__(256)
void k_spmm2(const u8* __restrict__ HL, const int* __restrict__ offL, const int* __restrict__ erowL, u8* __restrict__ XL,
             const u8* __restrict__ HP, const int* __restrict__ offP, const int* __restrict__ erowP, u8* __restrict__ XP) {
    int b = blockIdx.x;
    const u8* H; const int* off; const int* erow; u8* X; int c;
    int wib = threadIdx.x >> 6, lane = threadIdx.x & 63;
    if (b < 256) { H = HL; off = offL; erow = erowL; X = XL; c = b * 4 + wib; }
    else { b -= 256; H = HP; off = offP; erow = erowP; X = XP; c = b * 4 + wib; }
    int d0 = lane * 8;
    float acc[8] = {0,0,0,0,0,0,0,0};
    int e0 = off[c], e1 = off[c + 1];
    for (int e = e0; e < e1; ++e) {
        int r = erow[e];
        uint2 w = *(const uint2*)(H + (size_t)r * 512 + d0);
        acc[0] += fp8decw<0>(w.x);
        acc[1] += fp8decw<1>(w.x);
        acc[2] += fp8decw<2>(w.x);
        acc[3] += fp8decw<3>(w.x);
        acc[4] += fp8decw<0>(w.y);
        acc[5] += fp8decw<1>(w.y);
        acc[6] += fp8decw<2>(w.y);
        acc[7] += fp8decw<3>(w.y);
    }
    uint2 ow = *(const uint2*)(H + (size_t)c * 512 + d0);
    float o0 = fp8decw<0>(ow.x) + acc[0];
    float o1 = fp8decw<1>(ow.x) + acc[1];
    float o2 = fp8decw<2>(ow.x) + acc[2];
    float o3 = fp8decw<3>(ow.x) + acc[3];
    float o4 = fp8decw<0>(ow.y) + acc[4];
    float o5 = fp8decw<1>(ow.y) + acc[5];
    float o6 = fp8decw<2>(ow.y) + acc[6];
    float o7 = fp8decw<3>(ow.y) + acc[7];
    int lo = __builtin_amdgcn_cvt_pk_fp8_f32(o0, o1, 0, false);
    lo = __builtin_amdgcn_cvt_pk_fp8_f32(o2, o3, lo, true);
    int hi = __builtin_amdgcn_cvt_pk_fp8_f32(o4, o5, 0, false);
    hi = __builtin_amdgcn_cvt_pk_fp8_f32(o6, o7, hi, true);
    uint2 res; res.x = (uint32_t)lo; res.y = (uint32_t)hi;
    *(uint2*)(X + (size_t)c * 512 + d0) = res;
}

// ============================================================ scan (one-pass online softmax, unchanged)
__global__ __launch_bounds__(256)
void k_scan2(const bf16_t* __restrict__ S, const uint32_t* __restrict__ bits,
             const int* __restrict__ fm, const int* __restrict__ topo,
             const int* __restrict__ acts, const int* __restrict__ lastA,
             float* __restrict__ slogp, float* __restrict__ sent) {
    typedef bf16_t bf16x8 __attribute__((ext_vector_type(8)));
    const int NPn = 16384, cloud = NPn - 1;
    __shared__ float msh[256], zsh[256], wsh[256];
    __shared__ int ash[256];
    const int s = blockIdx.x, tid = threadIdx.x;
    const int i = topo[s], a = acts[i], last = lastA[s];
    const bf16_t* Srow = S + (size_t)i * NPn;
    const uint32_t* brow = bits + (size_t)i * 512;
    const int ml = fm[last] & 0xFFFF;
    const int baseCloud = (brow[511] >> 31) & 1;
    const int lic = (last == cloud);
    if (lic && baseCloud) {
        if (tid == 0) {
            float M = (float)Srow[cloud];
            slogp[s] = (a == cloud) ? 0.0f : (NEGV - M);
            sent[s] = 0.0f;
        }
        return;
    }
    float m = -3.4e38f, Z = 0.0f, W = 0.0f;
    int any = 0;
    if (!lic) {
        for (int c = 0; c < 8; ++c) {
            int j0 = c * 2048 + tid * 8;
            bf16x8 sv = *(const bf16x8*)(Srow + j0);
            uint32_t b8 = (brow[j0 >> 5] >> (j0 & 24)) & 0xFFu;
            int4 f0 = *(const int4*)(fm + j0);
            int4 f1 = *(const int4*)(fm + j0 + 4);
            int fj[8] = {f0.x, f0.y, f0.z, f0.w, f1.x, f1.y, f1.z, f1.w};
#pragma unroll
            for (int q = 0; q < 8; ++q) {
                int j = j0 + q;
                bool alw = ((b8 >> q) & 1) && ((fj[q] & 0xFFFF) >= ml)
                           && (j == last || (((unsigned)fj[q]) >> 16) >= (unsigned)s);
                if (alw) {
                    any = 1;
                    float l = (float)sv[q];
                    if (l > m) {
                        float d = m - l, ce = expf(d);
                        W = ce * (W + d * Z);
                        Z = ce * Z + 1.0f;
                        m = l;
                    } else {
                        float t = l - m, e = expf(t);
                        Z += e; W += t * e;
                    }
                }
            }
        }
    }
    msh[tid] = m; zsh[tid] = Z; wsh[tid] = W; ash[tid] = any;
    __syncthreads();
    for (int st = 128; st > 0; st >>= 1) {
        if (tid < st) {
            float m1 = msh[tid], Z1 = zsh[tid], W1 = wsh[tid];
            float m2 = msh[tid + st], Z2 = zsh[tid + st], W2 = wsh[tid + st];
            float M2 = fmaxf(m1, m2);
            float e1 = expf(m1 - M2), e2 = expf(m2 - M2);
            zsh[tid] = e1 * Z1 + e2 * Z2;
            wsh[tid] = e1 * (W1 + (m1 - M2) * Z1) + e2 * (W2 + (m2 - M2) * Z2);
            msh[tid] = M2;
            ash[tid] |= ash[tid + st];
        }
        __syncthreads();
    }
    if (tid != 0) return;
    if (ash[0]) {
        float M = msh[0], Zt = zsh[0], Wt = wsh[0];
        float logZ = logf(Zt);
        int fa = fm[a];
        bool alwa = ((brow[a >> 5] >> (a & 31)) & 1) && ((fa & 0xFFFF) >= ml)
                    && (a == last || (((unsigned)fa) >> 16) >= (unsigned)s);
        float la = alwa ? (float)Srow[a] : NEGV;
        slogp[s] = la - M - logZ;
        sent[s] = logZ - Wt / Zt;
        return;
    }
    int baseLast = (brow[last >> 5] >> (last & 31)) & 1;
    if (baseLast) { float M = (float)Srow[last]; slogp[s] = (a == last) ? 0.0f : (NEGV - M); sent[s] = 0.0f; return; }
    if (baseCloud) { float M = (float)Srow[cloud]; slogp[s] = (a == cloud) ? 0.0f : (NEGV - M); sent[s] = 0.0f; return; }
    float mm = -3.4e38f, ZZ = 0.0f, WW = 0.0f;
    for (int j = 0; j < NPn; ++j) {
        if ((brow[j >> 5] >> (j & 31)) & 1) {
            float l = (float)Srow[j];
            if (l > mm) { float d = mm - l, ce = expf(d); WW = ce * (WW + d * ZZ); ZZ = ce * ZZ + 1.0f; mm = l; }
            else { float t = l - mm, e = expf(t); ZZ += e; WW += t * e; }
        }
    }
    if (ZZ == 0.0f) { slogp[s] = -logf((float)NPn); sent[s] = logf((float)NPn); return; }
    float logZ = logf(ZZ);
    int ba = (brow[a >> 5] >> (a & 31)) & 1;
    float la = ba ? (float)Srow[a] : NEGV;
    slogp[s] = la - mm - logZ;
    sent[s] = logZ - WW / ZZ;
}

// ============================================================ value head + final
__global__ __launch_bounds__(256)
void k_pool2(const u8* __restrict__ HL, const u8* __restrict__ HP, float* __restrict__ pooled) {
    int b = blockIdx.x, tid = threadIdx.x;
    const u8* H; float* dst; int R, bb, ng; float inv;
    if (b < 16) { H = HL; dst = pooled; R = 1024; inv = 1.0f / 1024.0f; bb = b; ng = 16; }
    else { H = HP; dst = pooled + 512; R = 16384; inv = 1.0f / 16384.0f; bb = b - 16; ng = 128; }
    int c0 = tid * 2;                     // 2 contiguous cols per thread
    float a0 = 0, a1 = 0;
    for (int r = bb; r < R; r += ng) {
        uint32_t w = *(const unsigned short*)(H + (size_t)r * 512 + c0);
        a0 += fp8decw<0>(w);
        a1 += fp8decw<1>(w);
    }
    atomicAdd(&dst[c0], a0 * inv);
    atomicAdd(&dst[c0 + 1], a1 * inv);
}

__global__ __launch_bounds__(256)
void k_vpart(const float* __restrict__ pooled, const float* __restrict__ Wc1, float* __restrict__ hacc) {
    __shared__ float pk[128];
    int b = blockIdx.x, tid = threadIdx.x;
    int k0 = b * 128;
    if (tid < 128) pk[tid] = pooled[k0 + tid];
    __syncthreads();
    float a0 = 0, a1 = 0;
    for (int kk = 0; kk < 128; ++kk) {
        float pv = pk[kk];
        const float* wr = Wc1 + (size_t)(k0 + kk) * 512;
        a0 += pv * wr[tid];
        a1 += pv * wr[tid + 256];
    }
    atomicAdd(&hacc[tid], a0);
    atomicAdd(&hacc[tid + 256], a1);
}

__global__ __launch_bounds__(256)
void k_epilogue(const float* __restrict__ slogp, const float* __restrict__ sent,
                const float* __restrict__ hacc, const float* __restrict__ bc1,
                const float* __restrict__ wc2, float* __restrict__ out) {
    __shared__ float s1[256], s2[256], s3[256];
    int tid = threadIdx.x;
    float a = 0, b = 0;
    for (int k = tid; k < 1024; k += 256) { a += slogp[k]; b += sent[k]; }
    float v = fmaxf(hacc[tid] + bc1[tid], 0.0f) * wc2[tid]
            + fmaxf(hacc[tid + 256] + bc1[tid + 256], 0.0f) * wc2[tid + 256];
    s1[tid] = a; s2[tid] = b; s3[tid] = v;
    __syncthreads();
    for (int st = 128; st > 0; st >>= 1) {
        if (tid < st) { s1[tid] += s1[tid + st]; s2[tid] += s2[tid + st]; s3[tid] += s3[tid + st]; }
        __syncthreads();
    }
    if (tid == 0) { out[0] = s1[0]; out[1] = s2[0]; out[2] = s3[0]; }
}

// =======================================================================
extern "C" void kernel_launch(void* const* d_in, const int* in_sizes, int n_in,
                              void* d_out, int out_size, void* d_ws, size_t ws_size,
                              hipStream_t stream) {
    (void)n_in; (void)out_size; (void)ws_size; (void)in_sizes;
    const int MS = 1024, NP = 16384, EL = 4096, EP = 131072, D = 512;

    const int* logicE = (const int*)d_in[0];
    const float* logicF = (const float*)d_in[1];
    const int* physE = (const int*)d_in[2];
    const float* physF = (const float*)d_in[3];
    const int* acts = (const int*)d_in[4];
    const int* mask = (const int*)d_in[5];       // bool -> int32 on device
    const int* topo = (const int*)d_in[6];
    const float* Ws_in = (const float*)d_in[7];
    const float* Ws_out = (const float*)d_in[8];
    const float* Wp_in = (const float*)d_in[9];
    const float* Wp_out = (const float*)d_in[10];
    const float* sA1 = (const float*)d_in[11];
    const float* sA2 = (const float*)d_in[12];
    const float* pA1 = (const float*)d_in[13];
    const float* pA2 = (const float*)d_in[14];
    const float* Wq = (const float*)d_in[15];
    const float* Wk = (const float*)d_in[16];
    const float* Wc1 = (const float*)d_in[17];
    const float* bc1 = (const float*)d_in[18];
    const float* wc2 = (const float*)d_in[19];
    float* out = (float*)d_out;

    char* wsb = (char*)d_ws;
    size_t off = 0;
    auto alloc = [&](size_t bytes) -> void* {
        off = (off + 255) & ~(size_t)255;
        void* p = wsb + off; off += bytes; return p;
    };

    bf16_t* S_bf  = (bf16_t*)alloc((size_t)MS * NP * 2);
    u8* PB0     = (u8*)alloc((size_t)NP * D);
    u8* PB1     = (u8*)alloc((size_t)NP * D);
    u8* PB2     = (u8*)alloc((size_t)NP * D);
    u8* LB0     = (u8*)alloc((size_t)MS * D);
    u8* LB1     = (u8*)alloc((size_t)MS * D);
    u8* LB2     = (u8*)alloc((size_t)MS * D);
    u8* featsSb = (u8*)alloc((size_t)MS * 128);
    u8* featsPb = (u8*)alloc((size_t)NP * 128);
    u8* WsinT   = (u8*)alloc(512 * 128);
    u8* WpinT   = (u8*)alloc(512 * 128);
    u8* WsoutT  = (u8*)alloc(512 * 512);
    u8* sA1T    = (u8*)alloc(512 * 512);
    u8* sA2T    = (u8*)alloc(512 * 512);
    u8* WqT     = (u8*)alloc(512 * 512);
    u8* WpoutT  = (u8*)alloc(512 * 512);
    u8* pA1T    = (u8*)alloc(512 * 512);
    u8* pA2T    = (u8*)alloc(512 * 512);
    u8* WkT     = (u8*)alloc(512 * 512);
    uint32_t* bits = (uint32_t*)alloc((size_t)MS * NP / 8);   // 2 MB
    int* cntC  = (int*)alloc(NP * 4);
    int* offC  = (int*)alloc((NP + 1) * 4);
    int* curC  = (int*)alloc(NP * 4);
    int* cntR  = (int*)alloc(NP * 4);
    int* offR  = (int*)alloc((NP + 1) * 4);
    int* curR  = (int*)alloc(NP * 4);
    int* cntL  = (int*)alloc(MS * 4);
    int* offL  = (int*)alloc((MS + 1) * 4);
    int* curL  = (int*)alloc(MS * 4);
    int* erowCP = (int*)alloc(EP * 4);
    int* ecolRP = (int*)alloc(EP * 4);
    int* erowL  = (int*)alloc(EL * 4);
    int* firstL = (int*)alloc(NP * 4);
    int* lastA  = (int*)alloc(MS * 4);
    int* dist   = (int*)alloc(NP * 4);
    int* fm     = (int*)alloc(NP * 4);
    float* slogp = (float*)alloc(MS * 4);
    float* sentb = (float*)alloc(MS * 4);
    float* pooled = (float*)alloc(1024 * 4);
    float* hacc   = (float*)alloc(512 * 4);

    const int* rowP = physE;  const int* colP = physE + EP;
    const int* rowL = logicE; const int* colL = logicE + EL;

    // 1. prep (transposes + feat converts + mask bit-pack + zero-init)
    {
        PrepArgs p;
        const float* s512[8] = {Ws_out, sA1, sA2, Wq, Wp_out, pA1, pA2, Wk};
        u8* d512[8] = {WsoutT, sA1T, sA2T, WqT, WpoutT, pA1T, pA2T, WkT};
        for (int q = 0; q < 8; ++q) { p.w512src[q] = s512[q]; p.w512dst[q] = d512[q]; }
        p.w128src[0] = Ws_in; p.w128dst[0] = WsinT;
        p.w128src[1] = Wp_in; p.w128dst[1] = WpinT;
        p.logicF = logicF; p.physF = physF; p.featsSb = featsSb; p.featsPb = featsPb;
        p.mask = mask; p.bits = bits;
        p.cntC = cntC; p.cntR = cntR; p.cntL = cntL; p.firstL = firstL; p.dist = dist;
        p.pooled = pooled; p.hacc = hacc;
        hipLaunchKernelGGL(k_prep, dim3(4832), dim3(256), 0, stream, p);
    }
    // 2. CSR histogram + trajectory (fused)
    hipLaunchKernelGGL(k_hist3, dim3(1044), dim3(256), 0, stream,
                       rowP, colP, rowL, colL, cntC, cntR, cntL, EP, EL,
                       topo, acts, lastA, firstL);
    // 3-4. offsets + scatter
    hipLaunchKernelGGL(k_scan3, dim3(3), dim3(256), 0, stream,
                       cntC, offC, curC, cntR, offR, curR, cntL, offL, curL);
    hipLaunchKernelGGL(k_scatter3, dim3((2 * EP + EL) / 256), dim3(256), 0, stream,
                       rowP, colP, rowL, colL, curC, curR, curL, erowCP, ecolRP, erowL, EP, EL);
    // 5. BFS: 16 wide level dispatches (== 16 bounded Bellman-Ford iterations), then fm pack
    for (int lev = 0; lev < 16; ++lev)
        hipLaunchKernelGGL(k_bfs_level, dim3(64), dim3(256), 0, stream, offR, ecolRP, dist, lev);
    hipLaunchKernelGGL(k_fmpack, dim3(64), dim3(256), 0, stream, firstL, dist, fm);

    auto gemm2 = [&](const u8* A0, const u8* B0, const u8* C0, void* O0, float sc0,
                     const u8* A1, const u8* B1, const u8* C1, void* O1, float sc1,
                     int K, int relu) {
        GemmPair gp;
        gp.d0 = {A0, B0, C0, O0, 512, K, sc0, relu, 0};
        gp.d1 = {A1, B1, C1, O1, 512, K, sc1, relu, 0};
        gp.split = 8;
        hipLaunchKernelGGL(gemm_mfma, dim3(4, 136), dim3(256), 0, stream, gp);
    };

    // 6. h1 = relu(feats @ Win)
    gemm2(featsSb, WsinT, nullptr, LB0, 1.0f, featsPb, WpinT, nullptr, PB0, 1.0f, 128, 1);
    // 7. x = h1 + agg
    hipLaunchKernelGGL(k_spmm2, dim3(256 + 4096), dim3(256), 0, stream,
                       LB0, offL, erowL, LB1, PB0, offC, erowCP, PB1);
    // 8. h2 = relu(x @ Wout)
    gemm2(LB1, WsoutT, nullptr, LB0, 1.0f, PB1, WpoutT, nullptr, PB0, 1.0f, 512, 1);
    // 9. t = relu(h2 @ A1)
    gemm2(LB0, sA1T, nullptr, LB1, 1.0f, PB0, pA1T, nullptr, PB1, 1.0f, 512, 1);
    // 10. h = h2 + t @ A2
    gemm2(LB1, sA2T, LB0, LB2, 1.0f, PB1, pA2T, PB0, PB2, 1.0f, 512, 0);
    // 11. pooling
    hipLaunchKernelGGL(k_pool2, dim3(144), dim3(256), 0, stream, LB2, PB2, pooled);
    // 12. q = (h_s @ Wq)/sqrt(D);  Kp = h_p @ Wk
    gemm2(LB2, WqT, nullptr, LB1, 0.044194173824159216f, PB2, WkT, nullptr, PB1, 1.0f, 512, 0);
    // 13. S = q @ Kp^T   (bf16 output)
    {
        GemmPair gp;
        gp.d0 = {LB1, PB1, nullptr, S_bf, NP, 512, 1.0f, 0, 1};
        gp.d1 = gp.d0;
        gp.split = 1000;
        hipLaunchKernelGGL(gemm_mfma, dim3(128, 8), dim3(256), 0, stream, gp);
    }
    // 14. scan
    hipLaunchKernelGGL(k_scan2, dim3(MS), dim3(256), 0, stream,
                       S_bf, bits, fm, topo, acts, lastA, slogp, sentb);
    // 15-16. value head + final
    hipLaunchKernelGGL(k_vpart, dim3(8), dim3(256), 0, stream, pooled, Wc1, hacc);
    hipLaunchKernelGGL(k_epilogue, dim3(1), dim3(256), 0, stream, slogp, sentb, hacc, bc1, wc2, out);
}

// Round 16
// 349.762 us; speedup vs baseline: 1.3996x; 1.0809x over previous
//
#include <hip/hip_runtime.h>
#include <cstdint>
#include <cstddef>

typedef __bf16 bf16_t;
typedef uint8_t u8;
typedef u8 u8x4v __attribute__((ext_vector_type(4)));
typedef float f32x4 __attribute__((ext_vector_type(4)));

#define NEGV (-1e9f)

#define GLDS(gp, lp) __builtin_amdgcn_global_load_lds( \
    (const __attribute__((address_space(1))) void*)(gp), \
    (__attribute__((address_space(3))) void*)(lp), 16, 0, 0)

// ---------------- hardware OCP e4m3fn converts (gfx950 v_cvt, 1 VALU op each) ----------------
template<int SEL>
__device__ inline float fp8decw(uint32_t w) { return __builtin_amdgcn_cvt_f32_fp8((int)w, SEL); }
__device__ inline float fp8dec(u8 b) { return __builtin_amdgcn_cvt_f32_fp8((int)b, 0); }
__device__ inline u8 f2fp8(float x) {
    return (u8)(__builtin_amdgcn_cvt_pk_fp8_f32(x, x, 0, false) & 0xFF);
}

// ============================================================ prep mega-kernel
struct PrepArgs {
    const float* w512src[8]; u8* w512dst[8];
    const float* w128src[2]; u8* w128dst[2];
    const float* logicF; const float* physF;
    u8* featsSb; u8* featsPb;
    const int* mask; uint32_t* bits;
    int* cntC; int* cntR; int* cntL; int* firstL; int* dist;
    float* pooled; float* hacc;
};

__global__ __launch_bounds__(256)
void k_prep(PrepArgs p) {
    __shared__ float tb[64][65];
    const int b = blockIdx.x, tid = threadIdx.x;
    if (b < 544) {
        // transpose-convert f32 [K][N] -> fp8 [N][K], 64x64 tiles
        const float* src; u8* dst; int K, tile;
        if (b < 512) { src = p.w512src[b >> 6]; dst = p.w512dst[b >> 6]; K = 512; tile = b & 63; }
        else { int bb = b - 512; src = p.w128src[bb >> 4]; dst = p.w128dst[bb >> 4]; K = 128; tile = bb & 15; }
        const int N = 512;
        int kt = tile >> 3, tc = tile & 7;
        int cx = tid & 63, ry = tid >> 6;
#pragma unroll
        for (int q = 0; q < 16; ++q) {
            int r = q * 4 + ry;
            tb[r][cx] = src[(size_t)(kt * 64 + r) * N + tc * 64 + cx];
        }
        __syncthreads();
#pragma unroll
        for (int q = 0; q < 16; ++q) {
            int r2 = q * 4 + ry;
            dst[(size_t)(tc * 64 + r2) * K + kt * 64 + cx] = f2fp8(tb[cx][r2]);
        }
    } else if (b < 672) {
        size_t e0 = (size_t)(b - 544) * 1024 + tid * 4;
        float4 v = *(const float4*)(p.logicF + e0);
        int pk = __builtin_amdgcn_cvt_pk_fp8_f32(v.x, v.y, 0, false);
        pk = __builtin_amdgcn_cvt_pk_fp8_f32(v.z, v.w, pk, true);
        *(uint32_t*)(p.featsSb + e0) = (uint32_t)pk;
    } else if (b < 2720) {
        size_t e0 = (size_t)(b - 672) * 1024 + tid * 4;
        float4 v = *(const float4*)(p.physF + e0);
        int pk = __builtin_amdgcn_cvt_pk_fp8_f32(v.x, v.y, 0, false);
        pk = __builtin_amdgcn_cvt_pk_fp8_f32(v.z, v.w, pk, true);
        *(uint32_t*)(p.featsPb + e0) = (uint32_t)pk;
    } else if (b < 2784) {
        int gid = (b - 2720) * 256 + tid;   // 0..16383
        p.cntC[gid] = 0; p.cntR[gid] = 0; p.firstL[gid] = 0x7fffffff;
        p.dist[gid] = (gid == 0) ? 0 : 16384;
        if (gid < 1024) { p.cntL[gid] = 0; p.pooled[gid] = 0.0f; }
        if (gid < 512) p.hacc[gid] = 0.0f;
    } else {
        // mask bit-pack: 2048 blocks x 256 threads, 32 elems/thread
        size_t w = (size_t)(b - 2784) * 256 + tid;   // word index, 524288 total
        const int4* q4 = (const int4*)(p.mask + w * 32);
        uint32_t bb = 0;
#pragma unroll
        for (int q = 0; q < 8; ++q) {
            int4 v = q4[q];
            bb |= (v.x != 0 ? 1u : 0u) << (q * 4);
            bb |= (v.y != 0 ? 1u : 0u) << (q * 4 + 1);
            bb |= (v.z != 0 ? 1u : 0u) << (q * 4 + 2);
            bb |= (v.w != 0 ? 1u : 0u) << (q * 4 + 3);
        }
        p.bits[w] = bb;
    }
}

// ============================================================ CSR histogram + trajectory (fused)
__global__ void k_hist3(const int* __restrict__ rowP, const int* __restrict__ colP,
                        const int* __restrict__ rowL, const int* __restrict__ colL,
                        int* cntC, int* cntR, int* cntL, int EP, int EL,
                        const int* __restrict__ topo, const int* __restrict__ acts,
                        int* __restrict__ lastArr, int* __restrict__ firstL) {
    int b = blockIdx.x;
    if (b < 1040) {
        int e = b * 256 + threadIdx.x;
        if (e < EP) atomicAdd(&cntC[colP[e]], 1);
        else if (e < 2 * EP) atomicAdd(&cntR[rowP[e - EP]], 1);
        else if (e < 2 * EP + EL) atomicAdd(&cntL[colL[e - 2 * EP]], 1);
    } else {
        int s = (b - 1040) * 256 + threadIdx.x;   // 0..1023
        int last = (s == 0) ? 0 : acts[topo[s - 1]];
        lastArr[s] = last;
        int a = acts[topo[s]];
        if (a != last) atomicMin(&firstL[last], s);
    }
}

// ============================================================ prefix scan: register-resident, int4-vectorized
__global__ __launch_bounds__(256)
void k_scan3(int* cntC, int* offC, int* curC,
             int* cntR, int* offR, int* curR,
             int* cntL, int* offL, int* curL) {
    __shared__ int ss[256];
    const int tid = threadIdx.x;
    if (blockIdx.x < 2) {
        int* cnt; int* off; int* cur;
        if (blockIdx.x == 0) { cnt = cntC; off = offC; cur = curC; }
        else                 { cnt = cntR; off = offR; cur = curR; }
        // 16384 entries, 64/thread: one vectorized read pass into registers
        int4 v[16];
        const int4* pv = (const int4*)(cnt + tid * 64);
#pragma unroll
        for (int i = 0; i < 16; ++i) v[i] = pv[i];
        int s = 0;
#pragma unroll
        for (int i = 0; i < 16; ++i) s += v[i].x + v[i].y + v[i].z + v[i].w;
        ss[tid] = s; __syncthreads();
        for (int d = 1; d < 256; d <<= 1) {
            int t = (tid >= d) ? ss[tid - d] : 0;
            __syncthreads(); ss[tid] += t; __syncthreads();
        }
        int run = (tid == 0) ? 0 : ss[tid - 1];
        int4* po = (int4*)(off + tid * 64);
        int4* pc = (int4*)(cur + tid * 64);
#pragma unroll
        for (int i = 0; i < 16; ++i) {
            int4 o;
            o.x = run; run += v[i].x;
            o.y = run; run += v[i].y;
            o.z = run; run += v[i].z;
            o.w = run; run += v[i].w;
            po[i] = o; pc[i] = o;
        }
        if (tid == 255) off[16384] = run;
    } else {
        // 1024 entries, 4/thread
        int4 v = *(const int4*)(cntL + tid * 4);
        int s = v.x + v.y + v.z + v.w;
        ss[tid] = s; __syncthreads();
        for (int d = 1; d < 256; d <<= 1) {
            int t = (tid >= d) ? ss[tid - d] : 0;
            __syncthreads(); ss[tid] += t; __syncthreads();
        }
        int run = (tid == 0) ? 0 : ss[tid - 1];
        int4 o;
        o.x = run; run += v.x;
        o.y = run; run += v.y;
        o.z = run; run += v.z;
        o.w = run; run += v.w;
        *(int4*)(offL + tid * 4) = o;
        *(int4*)(curL + tid * 4) = o;
        if (tid == 255) offL[1024] = run;
    }
}

__global__ void k_scatter3(const int* __restrict__ rowP, const int* __restrict__ colP,
                           const int* __restrict__ rowL, const int* __restrict__ colL,
                           int* curC, int* curR, int* curL,
                           int* erowCP, int* ecolRP, int* erowL, int EP, int EL) {
    int e = blockIdx.x * 256 + threadIdx.x;
    if (e < EP) {
        int c = colP[e]; int q = atomicAdd(&curC[c], 1); erowCP[q] = rowP[e];
    } else if (e < 2 * EP) {
        int e2 = e - EP;
        int c = rowP[e2]; int q = atomicAdd(&curR[c], 1); ecolRP[q] = colP[e2];
    } else if (e < 2 * EP + EL) {
        int e3 = e - 2 * EP;
        int c = colL[e3]; int q = atomicAdd(&curL[c], 1); erowL[q] = rowL[e3];
    }
}

// ============================================================ BFS: one level per dispatch, full-GPU wide
__global__ __launch_bounds__(256)
void k_bfs_level(const int* __restrict__ offR, const int* __restrict__ ecol,
                 int* __restrict__ dist, int lev) {
    int j = blockIdx.x * 256 + threadIdx.x;
    if (dist[j] != lev) return;
    int e0 = offR[j], e1 = offR[j + 1];
    for (int e = e0; e < e1; ++e) {
        int v = ecol[e];
        if (dist[v] == 16384) dist[v] = lev + 1;
    }
}

__global__ __launch_bounds__(256)
void k_fmpack(const int* __restrict__ firstL, const int* __restrict__ dist, int* __restrict__ fm) {
    int j = blockIdx.x * 256 + threadIdx.x;
    int fl = firstL[j]; if (fl > 0xFFFF) fl = 0xFFFF;
    fm[j] = (fl << 16) | dist[j];
}

// ============================================================ GEMM fp8 (K_STEP=64, 2-buffer, swizzled, T1)
struct GemmDesc { const u8* A; const u8* B; const u8* Cin; void* O;
                  int N; int K; float scale; int relu; int obf; };
struct GemmPair { GemmDesc d0; GemmDesc d1; int split; };

__global__ __launch_bounds__(256)
void gemm_mfma(GemmPair args) {
    __shared__ u8 As[2][128 * 64];
    __shared__ u8 Bs[2][128 * 64];
    // T1: chunk-map flat block index so consecutive flat ids share an XCD L2 (nwg%8==0).
    const int nwg = gridDim.x * gridDim.y;
    const int cpx = nwg >> 3;
    const int pfl = blockIdx.y * gridDim.x + blockIdx.x;
    const int vfl = (pfl & 7) * cpx + (pfl >> 3);
    const int vbx = vfl % gridDim.x;
    const int vby = vfl / gridDim.x;
    const int inSet1 = (vby >= args.split);
    const GemmDesc g = inSet1 ? args.d1 : args.d0;
    const int my = vby - (inSet1 ? args.split : 0);
    const int m0 = my * 128, n0 = vbx * 128;
    const int tid = threadIdx.x, wave = tid >> 6, lane = tid & 63;
    const int wm = (wave >> 1) * 64, wn = (wave & 1) * 64;
    const int lr = lane & 15, lkq = lane >> 4;
    const int K = g.K;
    const int srr = wave * 16 + (lane >> 2);
    const int scb = (((lane & 3) ^ ((lane >> 2) & 3)) << 4);  // pre-swizzled global col byte
    const u8* Abase = g.A + (size_t)(m0 + srr) * K + scb;
    const u8* Bbase = g.B + (size_t)(n0 + srr) * K + scb;
    const size_t rstep = (size_t)64 * K;
    f32x4 acc[4][4] = {};

    auto stage = [&](int q, int k0) {
        GLDS(Abase + k0,         &As[q][(wave * 16) * 64]);
        GLDS(Abase + k0 + rstep, &As[q][(64 + wave * 16) * 64]);
        GLDS(Bbase + k0,         &Bs[q][(wave * 16) * 64]);
        GLDS(Bbase + k0 + rstep, &Bs[q][(64 + wave * 16) * 64]);
    };

    stage(0, 0);
    asm volatile("s_waitcnt vmcnt(0)" ::: "memory");
    __syncthreads();
    const int nt = K >> 6;
    for (int t = 0; t < nt; ++t) {
        int cur = t & 1;
        if (t + 1 < nt) stage(cur ^ 1, (t + 1) << 6);
#pragma unroll
        for (int kh = 0; kh < 2; ++kh) {
            long af[4], bf[4];
#pragma unroll
            for (int mi = 0; mi < 4; ++mi) {
                int r = wm + mi * 16 + lr;
                int pb = r * 64 + ((kh * 32 + lkq * 8) ^ ((r & 3) << 4));
                af[mi] = *(const long*)&As[cur][pb];
            }
#pragma unroll
            for (int ni = 0; ni < 4; ++ni) {
                int r = wn + ni * 16 + lr;
                int pb = r * 64 + ((kh * 32 + lkq * 8) ^ ((r & 3) << 4));
                bf[ni] = *(const long*)&Bs[cur][pb];
            }
#pragma unroll
            for (int mi = 0; mi < 4; ++mi)
#pragma unroll
                for (int ni = 0; ni < 4; ++ni)
                    acc[mi][ni] = __builtin_amdgcn_mfma_f32_16x16x32_fp8_fp8(af[mi], bf[ni], acc[mi][ni], 0, 0, 0);
        }
        asm volatile("s_waitcnt vmcnt(0)" ::: "memory");
        __syncthreads();
    }
    const int rb = m0 + wm + (lane >> 4) * 4;
    const int cb = n0 + wn + lr;
#pragma unroll
    for (int mi = 0; mi < 4; ++mi)
#pragma unroll
        for (int ni = 0; ni < 4; ++ni)
#pragma unroll
            for (int r = 0; r < 4; ++r) {
                int row = rb + mi * 16 + r;
                int col = cb + ni * 16;
                size_t idx = (size_t)row * g.N + col;
                float v = acc[mi][ni][r] * g.scale;
                if (g.Cin) v += fp8dec(g.Cin[idx]);
                if (g.relu) v = fmaxf(v, 0.0f);
                if (g.obf) ((bf16_t*)g.O)[idx] = (bf16_t)v;
                else       ((u8*)g.O)[idx] = f2fp8(v);
            }
}

// ============================================================ SpMM fp8 (fused logic+phys, hw cvt)
__global__ __launch_bounds__(256)
void k_spmm2(const u8* __restrict__ HL, const int* __restrict__ offL, const int* __restrict__ erowL, u8* __restrict__ XL,
             const u8* __restrict__ HP, const int* __restrict__ offP, const int* __restrict__ erowP, u8* __restrict__ XP) {
    int b = blockIdx.x;
    const u8* H; const int* off; const int* erow; u8* X; int c;
    int wib = threadIdx.x >> 6, lane = threadIdx.x & 63;
    if (b < 256) { H = HL; off = offL; erow = erowL; X = XL; c = b * 4 + wib; }
    else { b -= 256; H = HP; off = offP; erow = erowP; X = XP; c = b * 4 + wib; }
    int d0 = lane * 8;
    float acc[8] = {0,0,0,0,0,0,0,0};
    int e0 = off[c], e1 = off[c + 1];
    for (int e = e0; e < e1; ++e) {
        int r = erow[e];
        uint2 w = *(const uint2*)(H + (size_t)r * 512 + d0);
        acc[0] += fp8decw<0>(w.x);
        acc[1] += fp8decw<1>(w.x);
        acc[2] += fp8decw<2>(w.x);
        acc[3] += fp8decw<3>(w.x);
        acc[4] += fp8decw<0>(w.y);
        acc[5] += fp8decw<1>(w.y);
        acc[6] += fp8decw<2>(w.y);
        acc[7] += fp8decw<3>(w.y);
    }
    uint2 ow = *(const uint2*)(H + (size_t)c * 512 + d0);
    float o0 = fp8decw<0>(ow.x) + acc[0];
    float o1 = fp8decw<1>(ow.x) + acc[1];
    float o2 = fp8decw<2>(ow.x) + acc[2];
    float o3 = fp8decw<3>(ow.x) + acc[3];
    float o4 = fp8decw<0>(ow.y) + acc[4];
    float o5 = fp8decw<1>(ow.y) + acc[5];
    float o6 = fp8decw<2>(ow.y) + acc[6];
    float o7 = fp8decw<3>(ow.y) + acc[7];
    int lo = __builtin_amdgcn_cvt_pk_fp8_f32(o0, o1, 0, false);
    lo = __builtin_amdgcn_cvt_pk_fp8_f32(o2, o3, lo, true);
    int hi = __builtin_amdgcn_cvt_pk_fp8_f32(o4, o5, 0, false);
    hi = __builtin_amdgcn_cvt_pk_fp8_f32(o6, o7, hi, true);
    uint2 res; res.x = (uint32_t)lo; res.y = (uint32_t)hi;
    *(uint2*)(X + (size_t)c * 512 + d0) = res;
}

// ============================================================ scan (one-pass online softmax, unchanged)
__global__ __launch_bounds__(256)
void k_scan2(const bf16_t* __restrict__ S, const uint32_t* __restrict__ bits,
             const int* __restrict__ fm, const int* __restrict__ topo,
             const int* __restrict__ acts, const int* __restrict__ lastA,
             float* __restrict__ slogp, float* __restrict__ sent) {
    typedef bf16_t bf16x8 __attribute__((ext_vector_type(8)));
    const int NPn = 16384, cloud = NPn - 1;
    __shared__ float msh[256], zsh[256], wsh[256];
    __shared__ int ash[256];
    const int s = blockIdx.x, tid = threadIdx.x;
    const int i = topo[s], a = acts[i], last = lastA[s];
    const bf16_t* Srow = S + (size_t)i * NPn;
    const uint32_t* brow = bits + (size_t)i * 512;
    const int ml = fm[last] & 0xFFFF;
    const int baseCloud = (brow[511] >> 31) & 1;
    const int lic = (last == cloud);
    if (lic && baseCloud) {
        if (tid == 0) {
            float M = (float)Srow[cloud];
            slogp[s] = (a == cloud) ? 0.0f : (NEGV - M);
            sent[s] = 0.0f;
        }
        return;
    }
    float m = -3.4e38f, Z = 0.0f, W = 0.0f;
    int any = 0;
    if (!lic) {
        for (int c = 0; c < 8; ++c) {
            int j0 = c * 2048 + tid * 8;
            bf16x8 sv = *(const bf16x8*)(Srow + j0);
            uint32_t b8 = (brow[j0 >> 5] >> (j0 & 24)) & 0xFFu;
            int4 f0 = *(const int4*)(fm + j0);
            int4 f1 = *(const int4*)(fm + j0 + 4);
            int fj[8] = {f0.x, f0.y, f0.z, f0.w, f1.x, f1.y, f1.z, f1.w};
#pragma unroll
            for (int q = 0; q < 8; ++q) {
                int j = j0 + q;
                bool alw = ((b8 >> q) & 1) && ((fj[q] & 0xFFFF) >= ml)
                           && (j == last || (((unsigned)fj[q]) >> 16) >= (unsigned)s);
                if (alw) {
                    any = 1;
                    float l = (float)sv[q];
                    if (l > m) {
                        float d = m - l, ce = expf(d);
                        W = ce * (W + d * Z);
                        Z = ce * Z + 1.0f;
                        m = l;
                    } else {
                        float t = l - m, e = expf(t);
                        Z += e; W += t * e;
                    }
                }
            }
        }
    }
    msh[tid] = m; zsh[tid] = Z; wsh[tid] = W; ash[tid] = any;
    __syncthreads();
    for (int st = 128; st > 0; st >>= 1) {
        if (tid < st) {
            float m1 = msh[tid], Z1 = zsh[tid], W1 = wsh[tid];
            float m2 = msh[tid + st], Z2 = zsh[tid + st], W2 = wsh[tid + st];
            float M2 = fmaxf(m1, m2);
            float e1 = expf(m1 - M2), e2 = expf(m2 - M2);
            zsh[tid] = e1 * Z1 + e2 * Z2;
            wsh[tid] = e1 * (W1 + (m1 - M2) * Z1) + e2 * (W2 + (m2 - M2) * Z2);
            msh[tid] = M2;
            ash[tid] |= ash[tid + st];
        }
        __syncthreads();
    }
    if (tid != 0) return;
    if (ash[0]) {
        float M = msh[0], Zt = zsh[0], Wt = wsh[0];
        float logZ = logf(Zt);
        int fa = fm[a];
        bool alwa = ((brow[a >> 5] >> (a & 31)) & 1) && ((fa & 0xFFFF) >= ml)
                    && (a == last || (((unsigned)fa) >> 16) >= (unsigned)s);
        float la = alwa ? (float)Srow[a] : NEGV;
        slogp[s] = la - M - logZ;
        sent[s] = logZ - Wt / Zt;
        return;
    }
    int baseLast = (brow[last >> 5] >> (last & 31)) & 1;
    if (baseLast) { float M = (float)Srow[last]; slogp[s] = (a == last) ? 0.0f : (NEGV - M); sent[s] = 0.0f; return; }
    if (baseCloud) { float M = (float)Srow[cloud]; slogp[s] = (a == cloud) ? 0.0f : (NEGV - M); sent[s] = 0.0f; return; }
    float mm = -3.4e38f, ZZ = 0.0f, WW = 0.0f;
    for (int j = 0; j < NPn; ++j) {
        if ((brow[j >> 5] >> (j & 31)) & 1) {
            float l = (float)Srow[j];
            if (l > mm) { float d = mm - l, ce = expf(d); WW = ce * (WW + d * ZZ); ZZ = ce * ZZ + 1.0f; mm = l; }
            else { float t = l - mm, e = expf(t); ZZ += e; WW += t * e; }
        }
    }
    if (ZZ == 0.0f) { slogp[s] = -logf((float)NPn); sent[s] = logf((float)NPn); return; }
    float logZ = logf(ZZ);
    int ba = (brow[a >> 5] >> (a & 31)) & 1;
    float la = ba ? (float)Srow[a] : NEGV;
    slogp[s] = la - mm - logZ;
    sent[s] = logZ - WW / ZZ;
}

// ============================================================ value head + final
__global__ __launch_bounds__(256)
void k_pool2(const u8* __restrict__ HL, const u8* __restrict__ HP, float* __restrict__ pooled) {
    int b = blockIdx.x, tid = threadIdx.x;
    const u8* H; float* dst; int R, bb, ng; float inv;
    if (b < 16) { H = HL; dst = pooled; R = 1024; inv = 1.0f / 1024.0f; bb = b; ng = 16; }
    else { H = HP; dst = pooled + 512; R = 16384; inv = 1.0f / 16384.0f; bb = b - 16; ng = 128; }
    int c0 = tid * 2;                     // 2 contiguous cols per thread
    float a0 = 0, a1 = 0;
    for (int r = bb; r < R; r += ng) {
        uint32_t w = *(const unsigned short*)(H + (size_t)r * 512 + c0);
        a0 += fp8decw<0>(w);
        a1 += fp8decw<1>(w);
    }
    atomicAdd(&dst[c0], a0 * inv);
    atomicAdd(&dst[c0 + 1], a1 * inv);
}

__global__ __launch_bounds__(256)
void k_vpart(const float* __restrict__ pooled, const float* __restrict__ Wc1, float* __restrict__ hacc) {
    __shared__ float pk[128];
    int b = blockIdx.x, tid = threadIdx.x;
    int k0 = b * 128;
    if (tid < 128) pk[tid] = pooled[k0 + tid];
    __syncthreads();
    float a0 = 0, a1 = 0;
    for (int kk = 0; kk < 128; ++kk) {
        float pv = pk[kk];
        const float* wr = Wc1 + (size_t)(k0 + kk) * 512;
        a0 += pv * wr[tid];
        a1 += pv * wr[tid + 256];
    }
    atomicAdd(&hacc[tid], a0);
    atomicAdd(&hacc[tid + 256], a1);
}

__global__ __launch_bounds__(256)
void k_epilogue(const float* __restrict__ slogp, const float* __restrict__ sent,
                const float* __restrict__ hacc, const float* __restrict__ bc1,
                const float* __restrict__ wc2, float* __restrict__ out) {
    __shared__ float s1[256], s2[256], s3[256];
    int tid = threadIdx.x;
    float a = 0, b = 0;
    for (int k = tid; k < 1024; k += 256) { a += slogp[k]; b += sent[k]; }
    float v = fmaxf(hacc[tid] + bc1[tid], 0.0f) * wc2[tid]
            + fmaxf(hacc[tid + 256] + bc1[tid + 256], 0.0f) * wc2[tid + 256];
    s1[tid] = a; s2[tid] = b; s3[tid] = v;
    __syncthreads();
    for (int st = 128; st > 0; st >>= 1) {
        if (tid < st) { s1[tid] += s1[tid + st]; s2[tid] += s2[tid + st]; s3[tid] += s3[tid + st]; }
        __syncthreads();
    }
    if (tid == 0) { out[0] = s1[0]; out[1] = s2[0]; out[2] = s3[0]; }
}

// =======================================================================
extern "C" void kernel_launch(void* const* d_in, const int* in_sizes, int n_in,
                              void* d_out, int out_size, void* d_ws, size_t ws_size,
                              hipStream_t stream) {
    (void)n_in; (void)out_size; (void)ws_size; (void)in_sizes;
    const int MS = 1024, NP = 16384, EL = 4096, EP = 131072, D = 512;

    const int* logicE = (const int*)d_in[0];
    const float* logicF = (const float*)d_in[1];
    const int* physE = (const int*)d_in[2];
    const float* physF = (const float*)d_in[3];
    const int* acts = (const int*)d_in[4];
    const int* mask = (const int*)d_in[5];       // bool -> int32 on device
    const int* topo = (const int*)d_in[6];
    const float* Ws_in = (const float*)d_in[7];
    const float* Ws_out = (const float*)d_in[8];
    const float* Wp_in = (const float*)d_in[9];
    const float* Wp_out = (const float*)d_in[10];
    const float* sA1 = (const float*)d_in[11];
    const float* sA2 = (const float*)d_in[12];
    const float* pA1 = (const float*)d_in[13];
    const float* pA2 = (const float*)d_in[14];
    const float* Wq = (const float*)d_in[15];
    const float* Wk = (const float*)d_in[16];
    const float* Wc1 = (const float*)d_in[17];
    const float* bc1 = (const float*)d_in[18];
    const float* wc2 = (const float*)d_in[19];
    float* out = (float*)d_out;

    char* wsb = (char*)d_ws;
    size_t off = 0;
    auto alloc = [&](size_t bytes) -> void* {
        off = (off + 255) & ~(size_t)255;
        void* p = wsb + off; off += bytes; return p;
    };

    bf16_t* S_bf  = (bf16_t*)alloc((size_t)MS * NP * 2);
    u8* PB0     = (u8*)alloc((size_t)NP * D);
    u8* PB1     = (u8*)alloc((size_t)NP * D);
    u8* PB2     = (u8*)alloc((size_t)NP * D);
    u8* LB0     = (u8*)alloc((size_t)MS * D);
    u8* LB1     = (u8*)alloc((size_t)MS * D);
    u8* LB2     = (u8*)alloc((size_t)MS * D);
    u8* featsSb = (u8*)alloc((size_t)MS * 128);
    u8* featsPb = (u8*)alloc((size_t)NP * 128);
    u8* WsinT   = (u8*)alloc(512 * 128);
    u8* WpinT   = (u8*)alloc(512 * 128);
    u8* WsoutT  = (u8*)alloc(512 * 512);
    u8* sA1T    = (u8*)alloc(512 * 512);
    u8* sA2T    = (u8*)alloc(512 * 512);
    u8* WqT     = (u8*)alloc(512 * 512);
    u8* WpoutT  = (u8*)alloc(512 * 512);
    u8* pA1T    = (u8*)alloc(512 * 512);
    u8* pA2T    = (u8*)alloc(512 * 512);
    u8* WkT     = (u8*)alloc(512 * 512);
    uint32_t* bits = (uint32_t*)alloc((size_t)MS * NP / 8);   // 2 MB
    int* cntC  = (int*)alloc(NP * 4);
    int* offC  = (int*)alloc((NP + 1) * 4);
    int* curC  = (int*)alloc(NP * 4);
    int* cntR  = (int*)alloc(NP * 4);
    int* offR  = (int*)alloc((NP + 1) * 4);
    int* curR  = (int*)alloc(NP * 4);
    int* cntL  = (int*)alloc(MS * 4);
    int* offL  = (int*)alloc((MS + 1) * 4);
    int* curL  = (int*)alloc(MS * 4);
    int* erowCP = (int*)alloc(EP * 4);
    int* ecolRP = (int*)alloc(EP * 4);
    int* erowL  = (int*)alloc(EL * 4);
    int* firstL = (int*)alloc(NP * 4);
    int* lastA  = (int*)alloc(MS * 4);
    int* dist   = (int*)alloc(NP * 4);
    int* fm     = (int*)alloc(NP * 4);
    float* slogp = (float*)alloc(MS * 4);
    float* sentb = (float*)alloc(MS * 4);
    float* pooled = (float*)alloc(1024 * 4);
    float* hacc   = (float*)alloc(512 * 4);

    const int* rowP = physE;  const int* colP = physE + EP;
    const int* rowL = logicE; const int* colL = logicE + EL;

    // 1. prep (transposes + feat converts + mask bit-pack + zero-init)
    {
        PrepArgs p;
        const float* s512[8] = {Ws_out, sA1, sA2, Wq, Wp_out, pA1, pA2, Wk};
        u8* d512[8] = {WsoutT, sA1T, sA2T, WqT, WpoutT, pA1T, pA2T, WkT};
        for (int q = 0; q < 8; ++q) { p.w512src[q] = s512[q]; p.w512dst[q] = d512[q]; }
        p.w128src[0] = Ws_in; p.w128dst[0] = WsinT;
        p.w128src[1] = Wp_in; p.w128dst[1] = WpinT;
        p.logicF = logicF; p.physF = physF; p.featsSb = featsSb; p.featsPb = featsPb;
        p.mask = mask; p.bits = bits;
        p.cntC = cntC; p.cntR = cntR; p.cntL = cntL; p.firstL = firstL; p.dist = dist;
        p.pooled = pooled; p.hacc = hacc;
        hipLaunchKernelGGL(k_prep, dim3(4832), dim3(256), 0, stream, p);
    }
    // 2. CSR histogram + trajectory (fused)
    hipLaunchKernelGGL(k_hist3, dim3(1044), dim3(256), 0, stream,
                       rowP, colP, rowL, colL, cntC, cntR, cntL, EP, EL,
                       topo, acts, lastA, firstL);
    // 3-4. offsets + scatter
    hipLaunchKernelGGL(k_scan3, dim3(3), dim3(256), 0, stream,
                       cntC, offC, curC, cntR, offR, curR, cntL, offL, curL);
    hipLaunchKernelGGL(k_scatter3, dim3((2 * EP + EL) / 256), dim3(256), 0, stream,
                       rowP, colP, rowL, colL, curC, curR, curL, erowCP, ecolRP, erowL, EP, EL);
    // 5. BFS: 16 wide level dispatches (== 16 bounded Bellman-Ford iterations), then fm pack
    for (int lev = 0; lev < 16; ++lev)
        hipLaunchKernelGGL(k_bfs_level, dim3(64), dim3(256), 0, stream, offR, ecolRP, dist, lev);
    hipLaunchKernelGGL(k_fmpack, dim3(64), dim3(256), 0, stream, firstL, dist, fm);

    auto gemm2 = [&](const u8* A0, const u8* B0, const u8* C0, void* O0, float sc0,
                     const u8* A1, const u8* B1, const u8* C1, void* O1, float sc1,
                     int K, int relu) {
        GemmPair gp;
        gp.d0 = {A0, B0, C0, O0, 512, K, sc0, relu, 0};
        gp.d1 = {A1, B1, C1, O1, 512, K, sc1, relu, 0};
        gp.split = 8;
        hipLaunchKernelGGL(gemm_mfma, dim3(4, 136), dim3(256), 0, stream, gp);
    };

    // 6. h1 = relu(feats @ Win)
    gemm2(featsSb, WsinT, nullptr, LB0, 1.0f, featsPb, WpinT, nullptr, PB0, 1.0f, 128, 1);
    // 7. x = h1 + agg
    hipLaunchKernelGGL(k_spmm2, dim3(256 + 4096), dim3(256), 0, stream,
                       LB0, offL, erowL, LB1, PB0, offC, erowCP, PB1);
    // 8. h2 = relu(x @ Wout)
    gemm2(LB1, WsoutT, nullptr, LB0, 1.0f, PB1, WpoutT, nullptr, PB0, 1.0f, 512, 1);
    // 9. t = relu(h2 @ A1)
    gemm2(LB0, sA1T, nullptr, LB1, 1.0f, PB0, pA1T, nullptr, PB1, 1.0f, 512, 1);
    // 10. h = h2 + t @ A2
    gemm2(LB1, sA2T, LB0, LB2, 1.0f, PB1, pA2T, PB0, PB2, 1.0f, 512, 0);
    // 11. pooling
    hipLaunchKernelGGL(k_pool2, dim3(144), dim3(256), 0, stream, LB2, PB2, pooled);
    // 12. q = (h_s @ Wq)/sqrt(D);  Kp = h_p @ Wk
    gemm2(LB2, WqT, nullptr, LB1, 0.044194173824159216f, PB2, WkT, nullptr, PB1, 1.0f, 512, 0);
    // 13. S = q @ Kp^T   (bf16 output)
    {
        GemmPair gp;
        gp.d0 = {LB1, PB1, nullptr, S_bf, NP, 512, 1.0f, 0, 1};
        gp.d1 = gp.d0;
        gp.split = 1000;
        hipLaunchKernelGGL(gemm_mfma, dim3(128, 8), dim3(256), 0, stream, gp);
    }
    // 14. scan
    hipLaunchKernelGGL(k_scan2, dim3(MS), dim3(256), 0, stream,
                       S_bf, bits, fm, topo, acts, lastA, slogp, sentb);
    // 15-16. value head + final
    hipLaunchKernelGGL(k_vpart, dim3(8), dim3(256), 0, stream, pooled, Wc1, hacc);
    hipLaunchKernelGGL(k_epilogue, dim3(1), dim3(256), 0, stream, slogp, sentb, hacc, bc1, wc2, out);
}

// Round 17
// 336.723 us; speedup vs baseline: 1.4538x; 1.0387x over previous
//
#include <hip/hip_runtime.h>
#include <cstdint>
#include <cstddef>

typedef __bf16 bf16_t;
typedef uint8_t u8;
typedef float f32x4 __attribute__((ext_vector_type(4)));

#define NEGV (-1e9f)

#define GLDS(gp, lp) __builtin_amdgcn_global_load_lds( \
    (const __attribute__((address_space(1))) void*)(gp), \
    (__attribute__((address_space(3))) void*)(lp), 16, 0, 0)

// ---------------- hardware OCP e4m3fn converts ----------------
template<int SEL>
__device__ inline float fp8decw(uint32_t w) { return __builtin_amdgcn_cvt_f32_fp8((int)w, SEL); }
__device__ inline float fp8dec(u8 b) { return __builtin_amdgcn_cvt_f32_fp8((int)b, 0); }
__device__ inline u8 f2fp8(float x) {
    return (u8)(__builtin_amdgcn_cvt_pk_fp8_f32(x, x, 0, false) & 0xFF);
}

// ---------------- BFS level relax (shared by standalone + piggyback) ----------------
__device__ inline void bfs_level_work(const int* __restrict__ offR, const int* __restrict__ ecol,
                                      int* __restrict__ dist, int lev, int blk, int tid) {
    int j = blk * 256 + tid;
    if (dist[j] != lev) return;
    int e0 = offR[j], e1 = offR[j + 1];
    for (int e = e0; e < e1; ++e) {
        int v = ecol[e];
        if (dist[v] == 16384) dist[v] = lev + 1;
    }
}

// ============================================================ prep mega-kernel
struct PrepArgs {
    const float* w512src[8]; u8* w512dst[8];
    const float* w128src[2]; u8* w128dst[2];
    const float* logicF; const float* physF;
    u8* featsSb; u8* featsPb;
    const int* mask; uint32_t* bits;
    int* cntC; int* cntR; int* cntL; int* firstL; int* dist;
    float* pooled; float* hacc;
};

__global__ __launch_bounds__(256)
void k_prep(PrepArgs p) {
    __shared__ float tb[64][65];
    const int b = blockIdx.x, tid = threadIdx.x;
    if (b < 544) {
        const float* src; u8* dst; int K, tile;
        if (b < 512) { src = p.w512src[b >> 6]; dst = p.w512dst[b >> 6]; K = 512; tile = b & 63; }
        else { int bb = b - 512; src = p.w128src[bb >> 4]; dst = p.w128dst[bb >> 4]; K = 128; tile = bb & 15; }
        const int N = 512;
        int kt = tile >> 3, tc = tile & 7;
        int cx = tid & 63, ry = tid >> 6;
#pragma unroll
        for (int q = 0; q < 16; ++q) {
            int r = q * 4 + ry;
            tb[r][cx] = src[(size_t)(kt * 64 + r) * N + tc * 64 + cx];
        }
        __syncthreads();
#pragma unroll
        for (int q = 0; q < 16; ++q) {
            int r2 = q * 4 + ry;
            dst[(size_t)(tc * 64 + r2) * K + kt * 64 + cx] = f2fp8(tb[cx][r2]);
        }
    } else if (b < 672) {
        size_t e0 = (size_t)(b - 544) * 1024 + tid * 4;
        float4 v = *(const float4*)(p.logicF + e0);
        int pk = __builtin_amdgcn_cvt_pk_fp8_f32(v.x, v.y, 0, false);
        pk = __builtin_amdgcn_cvt_pk_fp8_f32(v.z, v.w, pk, true);
        *(uint32_t*)(p.featsSb + e0) = (uint32_t)pk;
    } else if (b < 2720) {
        size_t e0 = (size_t)(b - 672) * 1024 + tid * 4;
        float4 v = *(const float4*)(p.physF + e0);
        int pk = __builtin_amdgcn_cvt_pk_fp8_f32(v.x, v.y, 0, false);
        pk = __builtin_amdgcn_cvt_pk_fp8_f32(v.z, v.w, pk, true);
        *(uint32_t*)(p.featsPb + e0) = (uint32_t)pk;
    } else if (b < 2784) {
        int gid = (b - 2720) * 256 + tid;
        p.cntC[gid] = 0; p.cntR[gid] = 0; p.firstL[gid] = 0x7fffffff;
        p.dist[gid] = (gid == 0) ? 0 : 16384;
        if (gid < 1024) { p.cntL[gid] = 0; p.pooled[gid] = 0.0f; }
        if (gid < 512) p.hacc[gid] = 0.0f;
    } else {
        size_t w = (size_t)(b - 2784) * 256 + tid;
        const int4* q4 = (const int4*)(p.mask + w * 32);
        uint32_t bb = 0;
#pragma unroll
        for (int q = 0; q < 8; ++q) {
            int4 v = q4[q];
            bb |= (v.x != 0 ? 1u : 0u) << (q * 4);
            bb |= (v.y != 0 ? 1u : 0u) << (q * 4 + 1);
            bb |= (v.z != 0 ? 1u : 0u) << (q * 4 + 2);
            bb |= (v.w != 0 ? 1u : 0u) << (q * 4 + 3);
        }
        p.bits[w] = bb;
    }
}

// ============================================================ CSR histogram + trajectory (fused)
__global__ void k_hist3(const int* __restrict__ rowP, const int* __restrict__ colP,
                        const int* __restrict__ rowL, const int* __restrict__ colL,
                        int* cntC, int* cntR, int* cntL, int EP, int EL,
                        const int* __restrict__ topo, const int* __restrict__ acts,
                        int* __restrict__ lastArr, int* __restrict__ firstL) {
    int b = blockIdx.x;
    if (b < 1040) {
        int e = b * 256 + threadIdx.x;
        if (e < EP) atomicAdd(&cntC[colP[e]], 1);
        else if (e < 2 * EP) atomicAdd(&cntR[rowP[e - EP]], 1);
        else if (e < 2 * EP + EL) atomicAdd(&cntL[colL[e - 2 * EP]], 1);
    } else {
        int s = (b - 1040) * 256 + threadIdx.x;
        int last = (s == 0) ? 0 : acts[topo[s - 1]];
        lastArr[s] = last;
        int a = acts[topo[s]];
        if (a != last) atomicMin(&firstL[last], s);
    }
}

// ============================================================ prefix scan: register-resident, int4-vectorized
__global__ __launch_bounds__(256)
void k_scan3(int* cntC, int* offC, int* curC,
             int* cntR, int* offR, int* curR,
             int* cntL, int* offL, int* curL) {
    __shared__ int ss[256];
    const int tid = threadIdx.x;
    if (blockIdx.x < 2) {
        int* cnt; int* off; int* cur;
        if (blockIdx.x == 0) { cnt = cntC; off = offC; cur = curC; }
        else                 { cnt = cntR; off = offR; cur = curR; }
        int4 v[16];
        const int4* pv = (const int4*)(cnt + tid * 64);
#pragma unroll
        for (int i = 0; i < 16; ++i) v[i] = pv[i];
        int s = 0;
#pragma unroll
        for (int i = 0; i < 16; ++i) s += v[i].x + v[i].y + v[i].z + v[i].w;
        ss[tid] = s; __syncthreads();
        for (int d = 1; d < 256; d <<= 1) {
            int t = (tid >= d) ? ss[tid - d] : 0;
            __syncthreads(); ss[tid] += t; __syncthreads();
        }
        int run = (tid == 0) ? 0 : ss[tid - 1];
        int4* po = (int4*)(off + tid * 64);
        int4* pc = (int4*)(cur + tid * 64);
#pragma unroll
        for (int i = 0; i < 16; ++i) {
            int4 o;
            o.x = run; run += v[i].x;
            o.y = run; run += v[i].y;
            o.z = run; run += v[i].z;
            o.w = run; run += v[i].w;
            po[i] = o; pc[i] = o;
        }
        if (tid == 255) off[16384] = run;
    } else {
        int4 v = *(const int4*)(cntL + tid * 4);
        int s = v.x + v.y + v.z + v.w;
        ss[tid] = s; __syncthreads();
        for (int d = 1; d < 256; d <<= 1) {
            int t = (tid >= d) ? ss[tid - d] : 0;
            __syncthreads(); ss[tid] += t; __syncthreads();
        }
        int run = (tid == 0) ? 0 : ss[tid - 1];
        int4 o;
        o.x = run; run += v.x;
        o.y = run; run += v.y;
        o.z = run; run += v.z;
        o.w = run; run += v.w;
        *(int4*)(offL + tid * 4) = o;
        *(int4*)(curL + tid * 4) = o;
        if (tid == 255) offL[1024] = run;
    }
}

__global__ void k_scatter3(const int* __restrict__ rowP, const int* __restrict__ colP,
                           const int* __restrict__ rowL, const int* __restrict__ colL,
                           int* curC, int* curR, int* curL,
                           int* erowCP, int* ecolRP, int* erowL, int EP, int EL) {
    int e = blockIdx.x * 256 + threadIdx.x;
    if (e < EP) {
        int c = colP[e]; int q = atomicAdd(&curC[c], 1); erowCP[q] = rowP[e];
    } else if (e < 2 * EP) {
        int e2 = e - EP;
        int c = rowP[e2]; int q = atomicAdd(&curR[c], 1); ecolRP[q] = colP[e2];
    } else if (e < 2 * EP + EL) {
        int e3 = e - 2 * EP;
        int c = colL[e3]; int q = atomicAdd(&curL[c], 1); erowL[q] = rowL[e3];
    }
}

// ============================================================ BFS standalone level
__global__ __launch_bounds__(256)
void k_bfs_level(const int* __restrict__ offR, const int* __restrict__ ecol,
                 int* __restrict__ dist, int lev) {
    bfs_level_work(offR, ecol, dist, lev, blockIdx.x, threadIdx.x);
}

__global__ __launch_bounds__(256)
void k_fmpack(const int* __restrict__ firstL, const int* __restrict__ dist, int* __restrict__ fm) {
    int j = blockIdx.x * 256 + threadIdx.x;
    int fl = firstL[j]; if (fl > 0xFFFF) fl = 0xFFFF;
    fm[j] = (fl << 16) | dist[j];
}

// ============================================================ GEMM fp8 (K_STEP=64, 2-buffer, swizzled, T1)
// 1-D grid: blocks [0,64) run a piggybacked BFS level; blocks [64, 64+nwg) do GEMM.
struct GemmDesc { const u8* A; const u8* B; const u8* Cin; void* O;
                  int N; int K; float scale; int relu; int obf; };
struct GemmPair { GemmDesc d0; GemmDesc d1; int split; int gx; int nwg;
                  const int* offR; const int* ecol; int* dist; int bfsLev; };

__global__ __launch_bounds__(256)
void gemm_mfma(GemmPair args) {
    __shared__ u8 As[2][128 * 64];
    __shared__ u8 Bs[2][128 * 64];
    const int tid = threadIdx.x;
    int f = blockIdx.x;
    if (f < 64) {
        bfs_level_work(args.offR, args.ecol, args.dist, args.bfsLev, f, tid);
        return;
    }
    f -= 64;
    // T1: chunk-map flat id so consecutive ids share an XCD L2 (nwg % 8 == 0).
    const int cpx = args.nwg >> 3;
    const int vfl = (f & 7) * cpx + (f >> 3);
    const int vbx = vfl % args.gx;
    const int vby = vfl / args.gx;
    const int inSet1 = (vby >= args.split);
    const GemmDesc g = inSet1 ? args.d1 : args.d0;
    const int my = vby - (inSet1 ? args.split : 0);
    const int m0 = my * 128, n0 = vbx * 128;
    const int wave = tid >> 6, lane = tid & 63;
    const int wm = (wave >> 1) * 64, wn = (wave & 1) * 64;
    const int lr = lane & 15, lkq = lane >> 4;
    const int K = g.K;
    const int srr = wave * 16 + (lane >> 2);
    const int scb = (((lane & 3) ^ ((lane >> 2) & 3)) << 4);
    const u8* Abase = g.A + (size_t)(m0 + srr) * K + scb;
    const u8* Bbase = g.B + (size_t)(n0 + srr) * K + scb;
    const size_t rstep = (size_t)64 * K;
    f32x4 acc[4][4] = {};

    auto stage = [&](int q, int k0) {
        GLDS(Abase + k0,         &As[q][(wave * 16) * 64]);
        GLDS(Abase + k0 + rstep, &As[q][(64 + wave * 16) * 64]);
        GLDS(Bbase + k0,         &Bs[q][(wave * 16) * 64]);
        GLDS(Bbase + k0 + rstep, &Bs[q][(64 + wave * 16) * 64]);
    };

    stage(0, 0);
    asm volatile("s_waitcnt vmcnt(0)" ::: "memory");
    __syncthreads();
    const int nt = K >> 6;
    for (int t = 0; t < nt; ++t) {
        int cur = t & 1;
        if (t + 1 < nt) stage(cur ^ 1, (t + 1) << 6);
#pragma unroll
        for (int kh = 0; kh < 2; ++kh) {
            long af[4], bf[4];
#pragma unroll
            for (int mi = 0; mi < 4; ++mi) {
                int r = wm + mi * 16 + lr;
                int pb = r * 64 + ((kh * 32 + lkq * 8) ^ ((r & 3) << 4));
                af[mi] = *(const long*)&As[cur][pb];
            }
#pragma unroll
            for (int ni = 0; ni < 4; ++ni) {
                int r = wn + ni * 16 + lr;
                int pb = r * 64 + ((kh * 32 + lkq * 8) ^ ((r & 3) << 4));
                bf[ni] = *(const long*)&Bs[cur][pb];
            }
#pragma unroll
            for (int mi = 0; mi < 4; ++mi)
#pragma unroll
                for (int ni = 0; ni < 4; ++ni)
                    acc[mi][ni] = __builtin_amdgcn_mfma_f32_16x16x32_fp8_fp8(af[mi], bf[ni], acc[mi][ni], 0, 0, 0);
        }
        asm volatile("s_waitcnt vmcnt(0)" ::: "memory");
        __syncthreads();
    }
    const int rb = m0 + wm + (lane >> 4) * 4;
    const int cb = n0 + wn + lr;
#pragma unroll
    for (int mi = 0; mi < 4; ++mi)
#pragma unroll
        for (int ni = 0; ni < 4; ++ni)
#pragma unroll
            for (int r = 0; r < 4; ++r) {
                int row = rb + mi * 16 + r;
                int col = cb + ni * 16;
                size_t idx = (size_t)row * g.N + col;
                float v = acc[mi][ni][r] * g.scale;
                if (g.Cin) v += fp8dec(g.Cin[idx]);
                if (g.relu) v = fmaxf(v, 0.0f);
                if (g.obf) ((bf16_t*)g.O)[idx] = (bf16_t)v;
                else       ((u8*)g.O)[idx] = f2fp8(v);
            }
}

// ============================================================ SpMM fp8 (fused logic+phys, +BFS piggyback)
__global__ __launch_bounds__(256)
void k_spmm2(const u8* __restrict__ HL, const int* __restrict__ offL, const int* __restrict__ erowL, u8* __restrict__ XL,
             const u8* __restrict__ HP, const int* __restrict__ offP, const int* __restrict__ erowP, u8* __restrict__ XP,
             const int* __restrict__ offR, const int* __restrict__ ecol, int* __restrict__ dist, int bfsLev) {
    int b = blockIdx.x;
    if (b < 64) { bfs_level_work(offR, ecol, dist, bfsLev, b, threadIdx.x); return; }
    b -= 64;
    const u8* H; const int* off; const int* erow; u8* X; int c;
    int wib = threadIdx.x >> 6, lane = threadIdx.x & 63;
    if (b < 256) { H = HL; off = offL; erow = erowL; X = XL; c = b * 4 + wib; }
    else { b -= 256; H = HP; off = offP; erow = erowP; X = XP; c = b * 4 + wib; }
    int d0 = lane * 8;
    float acc[8] = {0,0,0,0,0,0,0,0};
    int e0 = off[c], e1 = off[c + 1];
    for (int e = e0; e < e1; ++e) {
        int r = erow[e];
        uint2 w = *(const uint2*)(H + (size_t)r * 512 + d0);
        acc[0] += fp8decw<0>(w.x);
        acc[1] += fp8decw<1>(w.x);
        acc[2] += fp8decw<2>(w.x);
        acc[3] += fp8decw<3>(w.x);
        acc[4] += fp8decw<0>(w.y);
        acc[5] += fp8decw<1>(w.y);
        acc[6] += fp8decw<2>(w.y);
        acc[7] += fp8decw<3>(w.y);
    }
    uint2 ow = *(const uint2*)(H + (size_t)c * 512 + d0);
    float o0 = fp8decw<0>(ow.x) + acc[0];
    float o1 = fp8decw<1>(ow.x) + acc[1];
    float o2 = fp8decw<2>(ow.x) + acc[2];
    float o3 = fp8decw<3>(ow.x) + acc[3];
    float o4 = fp8decw<0>(ow.y) + acc[4];
    float o5 = fp8decw<1>(ow.y) + acc[5];
    float o6 = fp8decw<2>(ow.y) + acc[6];
    float o7 = fp8decw<3>(ow.y) + acc[7];
    int lo = __builtin_amdgcn_cvt_pk_fp8_f32(o0, o1, 0, false);
    lo = __builtin_amdgcn_cvt_pk_fp8_f32(o2, o3, lo, true);
    int hi = __builtin_amdgcn_cvt_pk_fp8_f32(o4, o5, 0, false);
    hi = __builtin_amdgcn_cvt_pk_fp8_f32(o6, o7, hi, true);
    uint2 res; res.x = (uint32_t)lo; res.y = (uint32_t)hi;
    *(uint2*)(X + (size_t)c * 512 + d0) = res;
}

// ============================================================ scan (one-pass online softmax)
__global__ __launch_bounds__(256)
void k_scan2(const bf16_t* __restrict__ S, const uint32_t* __restrict__ bits,
             const int* __restrict__ fm, const int* __restrict__ topo,
             const int* __restrict__ acts, const int* __restrict__ lastA,
             float* __restrict__ slogp, float* __restrict__ sent) {
    typedef bf16_t bf16x8 __attribute__((ext_vector_type(8)));
    const int NPn = 16384, cloud = NPn - 1;
    __shared__ float msh[256], zsh[256], wsh[256];
    __shared__ int ash[256];
    const int s = blockIdx.x, tid = threadIdx.x;
    const int i = topo[s], a = acts[i], last = lastA[s];
    const bf16_t* Srow = S + (size_t)i * NPn;
    const uint32_t* brow = bits + (size_t)i * 512;
    const int ml = fm[last] & 0xFFFF;
    const int baseCloud = (brow[511] >> 31) & 1;
    const int lic = (last == cloud);
    if (lic && baseCloud) {
        if (tid == 0) {
            float M = (float)Srow[cloud];
            slogp[s] = (a == cloud) ? 0.0f : (NEGV - M);
            sent[s] = 0.0f;
        }
        return;
    }
    float m = -3.4e38f, Z = 0.0f, W = 0.0f;
    int any = 0;
    if (!lic) {
        for (int c = 0; c < 8; ++c) {
            int j0 = c * 2048 + tid * 8;
            bf16x8 sv = *(const bf16x8*)(Srow + j0);
            uint32_t b8 = (brow[j0 >> 5] >> (j0 & 24)) & 0xFFu;
            int4 f0 = *(const int4*)(fm + j0);
            int4 f1 = *(const int4*)(fm + j0 + 4);
            int fj[8] = {f0.x, f0.y, f0.z, f0.w, f1.x, f1.y, f1.z, f1.w};
#pragma unroll
            for (int q = 0; q < 8; ++q) {
                int j = j0 + q;
                bool alw = ((b8 >> q) & 1) && ((fj[q] & 0xFFFF) >= ml)
                           && (j == last || (((unsigned)fj[q]) >> 16) >= (unsigned)s);
                if (alw) {
                    any = 1;
                    float l = (float)sv[q];
                    if (l > m) {
                        float d = m - l, ce = expf(d);
                        W = ce * (W + d * Z);
                        Z = ce * Z + 1.0f;
                        m = l;
                    } else {
                        float t = l - m, e = expf(t);
                        Z += e; W += t * e;
                    }
                }
            }
        }
    }
    msh[tid] = m; zsh[tid] = Z; wsh[tid] = W; ash[tid] = any;
    __syncthreads();
    for (int st = 128; st > 0; st >>= 1) {
        if (tid < st) {
            float m1 = msh[tid], Z1 = zsh[tid], W1 = wsh[tid];
            float m2 = msh[tid + st], Z2 = zsh[tid + st], W2 = wsh[tid + st];
            float M2 = fmaxf(m1, m2);
            float e1 = expf(m1 - M2), e2 = expf(m2 - M2);
            zsh[tid] = e1 * Z1 + e2 * Z2;
            wsh[tid] = e1 * (W1 + (m1 - M2) * Z1) + e2 * (W2 + (m2 - M2) * Z2);
            msh[tid] = M2;
            ash[tid] |= ash[tid + st];
        }
        __syncthreads();
    }
    if (tid != 0) return;
    if (ash[0]) {
        float M = msh[0], Zt = zsh[0], Wt = wsh[0];
        float logZ = logf(Zt);
        int fa = fm[a];
        bool alwa = ((brow[a >> 5] >> (a & 31)) & 1) && ((fa & 0xFFFF) >= ml)
                    && (a == last || (((unsigned)fa) >> 16) >= (unsigned)s);
        float la = alwa ? (float)Srow[a] : NEGV;
        slogp[s] = la - M - logZ;
        sent[s] = logZ - Wt / Zt;
        return;
    }
    int baseLast = (brow[last >> 5] >> (last & 31)) & 1;
    if (baseLast) { float M = (float)Srow[last]; slogp[s] = (a == last) ? 0.0f : (NEGV - M); sent[s] = 0.0f; return; }
    if (baseCloud) { float M = (float)Srow[cloud]; slogp[s] = (a == cloud) ? 0.0f : (NEGV - M); sent[s] = 0.0f; return; }
    float mm = -3.4e38f, ZZ = 0.0f, WW = 0.0f;
    for (int j = 0; j < NPn; ++j) {
        if ((brow[j >> 5] >> (j & 31)) & 1) {
            float l = (float)Srow[j];
            if (l > mm) { float d = mm - l, ce = expf(d); WW = ce * (WW + d * ZZ); ZZ = ce * ZZ + 1.0f; mm = l; }
            else { float t = l - mm, e = expf(t); ZZ += e; WW += t * e; }
        }
    }
    if (ZZ == 0.0f) { slogp[s] = -logf((float)NPn); sent[s] = logf((float)NPn); return; }
    float logZ = logf(ZZ);
    int ba = (brow[a >> 5] >> (a & 31)) & 1;
    float la = ba ? (float)Srow[a] : NEGV;
    slogp[s] = la - mm - logZ;
    sent[s] = logZ - WW / ZZ;
}

// ============================================================ value head + final (+BFS piggyback on pool)
__global__ __launch_bounds__(256)
void k_pool2(const u8* __restrict__ HL, const u8* __restrict__ HP, float* __restrict__ pooled,
             const int* __restrict__ offR, const int* __restrict__ ecol, int* __restrict__ dist, int bfsLev) {
    int b = blockIdx.x, tid = threadIdx.x;
    if (b < 64) { bfs_level_work(offR, ecol, dist, bfsLev, b, tid); return; }
    b -= 64;
    const u8* H; float* dst; int R, bb, ng; float inv;
    if (b < 16) { H = HL; dst = pooled; R = 1024; inv = 1.0f / 1024.0f; bb = b; ng = 16; }
    else { H = HP; dst = pooled + 512; R = 16384; inv = 1.0f / 16384.0f; bb = b - 16; ng = 128; }
    int c0 = tid * 2;
    float a0 = 0, a1 = 0;
    for (int r = bb; r < R; r += ng) {
        uint32_t w = *(const unsigned short*)(H + (size_t)r * 512 + c0);
        a0 += fp8decw<0>(w);
        a1 += fp8decw<1>(w);
    }
    atomicAdd(&dst[c0], a0 * inv);
    atomicAdd(&dst[c0 + 1], a1 * inv);
}

__global__ __launch_bounds__(256)
void k_vpart(const float* __restrict__ pooled, const float* __restrict__ Wc1, float* __restrict__ hacc) {
    __shared__ float pk[128];
    int b = blockIdx.x, tid = threadIdx.x;
    int k0 = b * 128;
    if (tid < 128) pk[tid] = pooled[k0 + tid];
    __syncthreads();
    float a0 = 0, a1 = 0;
    for (int kk = 0; kk < 128; ++kk) {
        float pv = pk[kk];
        const float* wr = Wc1 + (size_t)(k0 + kk) * 512;
        a0 += pv * wr[tid];
        a1 += pv * wr[tid + 256];
    }
    atomicAdd(&hacc[tid], a0);
    atomicAdd(&hacc[tid + 256], a1);
}

__global__ __launch_bounds__(256)
void k_epilogue(const float* __restrict__ slogp, const float* __restrict__ sent,
                const float* __restrict__ hacc, const float* __restrict__ bc1,
                const float* __restrict__ wc2, float* __restrict__ out) {
    __shared__ float s1[256], s2[256], s3[256];
    int tid = threadIdx.x;
    float a = 0, b = 0;
    for (int k = tid; k < 1024; k += 256) { a += slogp[k]; b += sent[k]; }
    float v = fmaxf(hacc[tid] + bc1[tid], 0.0f) * wc2[tid]
            + fmaxf(hacc[tid + 256] + bc1[tid + 256], 0.0f) * wc2[tid + 256];
    s1[tid] = a; s2[tid] = b; s3[tid] = v;
    __syncthreads();
    for (int st = 128; st > 0; st >>= 1) {
        if (tid < st) { s1[tid] += s1[tid + st]; s2[tid] += s2[tid + st]; s3[tid] += s3[tid + st]; }
        __syncthreads();
    }
    if (tid == 0) { out[0] = s1[0]; out[1] = s2[0]; out[2] = s3[0]; }
}

// =======================================================================
extern "C" void kernel_launch(void* const* d_in, const int* in_sizes, int n_in,
                              void* d_out, int out_size, void* d_ws, size_t ws_size,
                              hipStream_t stream) {
    (void)n_in; (void)out_size; (void)ws_size; (void)in_sizes;
    const int MS = 1024, NP = 16384, EL = 4096, EP = 131072, D = 512;

    const int* logicE = (const int*)d_in[0];
    const float* logicF = (const float*)d_in[1];
    const int* physE = (const int*)d_in[2];
    const float* physF = (const float*)d_in[3];
    const int* acts = (const int*)d_in[4];
    const int* mask = (const int*)d_in[5];
    const int* topo = (const int*)d_in[6];
    const float* Ws_in = (const float*)d_in[7];
    const float* Ws_out = (const float*)d_in[8];
    const float* Wp_in = (const float*)d_in[9];
    const float* Wp_out = (const float*)d_in[10];
    const float* sA1 = (const float*)d_in[11];
    const float* sA2 = (const float*)d_in[12];
    const float* pA1 = (const float*)d_in[13];
    const float* pA2 = (const float*)d_in[14];
    const float* Wq = (const float*)d_in[15];
    const float* Wk = (const float*)d_in[16];
    const float* Wc1 = (const float*)d_in[17];
    const float* bc1 = (const float*)d_in[18];
    const float* wc2 = (const float*)d_in[19];
    float* out = (float*)d_out;

    char* wsb = (char*)d_ws;
    size_t off = 0;
    auto alloc = [&](size_t bytes) -> void* {
        off = (off + 255) & ~(size_t)255;
        void* p = wsb + off; off += bytes; return p;
    };

    bf16_t* S_bf  = (bf16_t*)alloc((size_t)MS * NP * 2);
    u8* PB0     = (u8*)alloc((size_t)NP * D);
    u8* PB1     = (u8*)alloc((size_t)NP * D);
    u8* PB2     = (u8*)alloc((size_t)NP * D);
    u8* LB0     = (u8*)alloc((size_t)MS * D);
    u8* LB1     = (u8*)alloc((size_t)MS * D);
    u8* LB2     = (u8*)alloc((size_t)MS * D);
    u8* featsSb = (u8*)alloc((size_t)MS * 128);
    u8* featsPb = (u8*)alloc((size_t)NP * 128);
    u8* WsinT   = (u8*)alloc(512 * 128);
    u8* WpinT   = (u8*)alloc(512 * 128);
    u8* WsoutT  = (u8*)alloc(512 * 512);
    u8* sA1T    = (u8*)alloc(512 * 512);
    u8* sA2T    = (u8*)alloc(512 * 512);
    u8* WqT     = (u8*)alloc(512 * 512);
    u8* WpoutT  = (u8*)alloc(512 * 512);
    u8* pA1T    = (u8*)alloc(512 * 512);
    u8* pA2T    = (u8*)alloc(512 * 512);
    u8* WkT     = (u8*)alloc(512 * 512);
    uint32_t* bits = (uint32_t*)alloc((size_t)MS * NP / 8);
    int* cntC  = (int*)alloc(NP * 4);
    int* offC  = (int*)alloc((NP + 1) * 4);
    int* curC  = (int*)alloc(NP * 4);
    int* cntR  = (int*)alloc(NP * 4);
    int* offR  = (int*)alloc((NP + 1) * 4);
    int* curR  = (int*)alloc(NP * 4);
    int* cntL  = (int*)alloc(MS * 4);
    int* offL  = (int*)alloc((MS + 1) * 4);
    int* curL  = (int*)alloc(MS * 4);
    int* erowCP = (int*)alloc(EP * 4);
    int* ecolRP = (int*)alloc(EP * 4);
    int* erowL  = (int*)alloc(EL * 4);
    int* firstL = (int*)alloc(NP * 4);
    int* lastA  = (int*)alloc(MS * 4);
    int* dist   = (int*)alloc(NP * 4);
    int* fm     = (int*)alloc(NP * 4);
    float* slogp = (float*)alloc(MS * 4);
    float* sentb = (float*)alloc(MS * 4);
    float* pooled = (float*)alloc(1024 * 4);
    float* hacc   = (float*)alloc(512 * 4);

    const int* rowP = physE;  const int* colP = physE + EP;
    const int* rowL = logicE; const int* colL = logicE + EL;

    // 1. prep
    {
        PrepArgs p;
        const float* s512[8] = {Ws_out, sA1, sA2, Wq, Wp_out, pA1, pA2, Wk};
        u8* d512[8] = {WsoutT, sA1T, sA2T, WqT, WpoutT, pA1T, pA2T, WkT};
        for (int q = 0; q < 8; ++q) { p.w512src[q] = s512[q]; p.w512dst[q] = d512[q]; }
        p.w128src[0] = Ws_in; p.w128dst[0] = WsinT;
        p.w128src[1] = Wp_in; p.w128dst[1] = WpinT;
        p.logicF = logicF; p.physF = physF; p.featsSb = featsSb; p.featsPb = featsPb;
        p.mask = mask; p.bits = bits;
        p.cntC = cntC; p.cntR = cntR; p.cntL = cntL; p.firstL = firstL; p.dist = dist;
        p.pooled = pooled; p.hacc = hacc;
        hipLaunchKernelGGL(k_prep, dim3(4832), dim3(256), 0, stream, p);
    }
    // 2. CSR histogram + trajectory
    hipLaunchKernelGGL(k_hist3, dim3(1044), dim3(256), 0, stream,
                       rowP, colP, rowL, colL, cntC, cntR, cntL, EP, EL,
                       topo, acts, lastA, firstL);
    // 3-4. offsets + scatter
    hipLaunchKernelGGL(k_scan3, dim3(3), dim3(256), 0, stream,
                       cntC, offC, curC, cntR, offR, curR, cntL, offL, curL);
    hipLaunchKernelGGL(k_scatter3, dim3((2 * EP + EL) / 256), dim3(256), 0, stream,
                       rowP, colP, rowL, colL, curC, curR, curL, erowCP, ecolRP, erowL, EP, EL);
    // 5. BFS standalone levels 0..6 (levels 7..14 ride the pipeline; 15 + fmpack after)
    for (int lev = 0; lev < 7; ++lev)
        hipLaunchKernelGGL(k_bfs_level, dim3(64), dim3(256), 0, stream, offR, ecolRP, dist, lev);

    auto gemm2 = [&](const u8* A0, const u8* B0, const u8* C0, void* O0, float sc0,
                     const u8* A1, const u8* B1, const u8* C1, void* O1, float sc1,
                     int K, int relu, int bfsLev) {
        GemmPair gp;
        gp.d0 = {A0, B0, C0, O0, 512, K, sc0, relu, 0};
        gp.d1 = {A1, B1, C1, O1, 512, K, sc1, relu, 0};
        gp.split = 8; gp.gx = 4; gp.nwg = 544;
        gp.offR = offR; gp.ecol = ecolRP; gp.dist = dist; gp.bfsLev = bfsLev;
        hipLaunchKernelGGL(gemm_mfma, dim3(64 + 544), dim3(256), 0, stream, gp);
    };

    // 6. h1 = relu(feats @ Win)                       [+BFS L7]
    gemm2(featsSb, WsinT, nullptr, LB0, 1.0f, featsPb, WpinT, nullptr, PB0, 1.0f, 128, 1, 7);
    // 7. x = h1 + agg                                  [+BFS L8]
    hipLaunchKernelGGL(k_spmm2, dim3(64 + 256 + 4096), dim3(256), 0, stream,
                       LB0, offL, erowL, LB1, PB0, offC, erowCP, PB1,
                       offR, ecolRP, dist, 8);
    // 8. h2 = relu(x @ Wout)                           [+BFS L9]
    gemm2(LB1, WsoutT, nullptr, LB0, 1.0f, PB1, WpoutT, nullptr, PB0, 1.0f, 512, 1, 9);
    // 9. t = relu(h2 @ A1)                             [+BFS L10]
    gemm2(LB0, sA1T, nullptr, LB1, 1.0f, PB0, pA1T, nullptr, PB1, 1.0f, 512, 1, 10);
    // 10. h = h2 + t @ A2                              [+BFS L11]
    gemm2(LB1, sA2T, LB0, LB2, 1.0f, PB1, pA2T, PB0, PB2, 1.0f, 512, 0, 11);
    // 11. pooling                                      [+BFS L12]
    hipLaunchKernelGGL(k_pool2, dim3(64 + 144), dim3(256), 0, stream, LB2, PB2, pooled,
                       offR, ecolRP, dist, 12);
    // 12. q, Kp                                        [+BFS L13]
    gemm2(LB2, WqT, nullptr, LB1, 0.044194173824159216f, PB2, WkT, nullptr, PB1, 1.0f, 512, 0, 13);
    // 13. S = q @ Kp^T                                 [+BFS L14]
    {
        GemmPair gp;
        gp.d0 = {LB1, PB1, nullptr, S_bf, NP, 512, 1.0f, 0, 1};
        gp.d1 = gp.d0;
        gp.split = 1000; gp.gx = 128; gp.nwg = 1024;
        gp.offR = offR; gp.ecol = ecolRP; gp.dist = dist; gp.bfsLev = 14;
        hipLaunchKernelGGL(gemm_mfma, dim3(64 + 1024), dim3(256), 0, stream, gp);
    }
    // 14. BFS level 15 + fm pack
    hipLaunchKernelGGL(k_bfs_level, dim3(64), dim3(256), 0, stream, offR, ecolRP, dist, 15);
    hipLaunchKernelGGL(k_fmpack, dim3(64), dim3(256), 0, stream, firstL, dist, fm);
    // 15. scan
    hipLaunchKernelGGL(k_scan2, dim3(MS), dim3(256), 0, stream,
                       S_bf, bits, fm, topo, acts, lastA, slogp, sentb);
    // 16-17. value head + final
    hipLaunchKernelGGL(k_vpart, dim3(8), dim3(256), 0, stream, pooled, Wc1, hacc);
    hipLaunchKernelGGL(k_epilogue, dim3(1), dim3(256), 0, stream, slogp, sentb, hacc, bc1, wc2, out);
}